// Round 1
// baseline (1290.035 us; speedup 1.0000x reference)
//
#include <hip/hip_runtime.h>
#include <hip/hip_bf16.h>
#include <cmath>

// Problem constants
#define NN 50000
#define EE 800000
#define ET 850000   // EE + NN self loops
#define HH 4
#define CC1 128
#define CC2 64
#define FIN 256
#define NCLS 50

// ---------------- fp32 tiled GEMM: C[M,N] = A[M,K] @ B[K,N] (+bias) ----------
// BM=64, BN=64, BK=16, 256 threads, 4x4 per thread. K must be % 16.
__global__ __launch_bounds__(256) void gemm_f32(
    const float* __restrict__ A, const float* __restrict__ B,
    const float* __restrict__ bias, float* __restrict__ C,
    int M, int N, int K)
{
    __shared__ float As[16][64 + 4];
    __shared__ float Bs[16][64 + 4];
    int tid = threadIdx.x;
    int row0 = blockIdx.x * 64;
    int col0 = blockIdx.y * 64;
    int tx = tid & 15;   // col group (0..15)
    int ty = tid >> 4;   // row group (0..15)
    float acc[4][4] = {{0.f}};

    int a_r = tid >> 2;          // 0..63 row within tile
    int a_c = (tid & 3) << 2;    // 0,4,8,12 k within tile
    int b_r = tid >> 4;          // 0..15 k within tile
    int b_c = (tid & 15) << 2;   // 0..60 col within tile
    bool n4 = ((N & 3) == 0);

    for (int k0 = 0; k0 < K; k0 += 16) {
        // load A tile (64x16)
        {
            int gr = row0 + a_r;
            float4 v = make_float4(0.f, 0.f, 0.f, 0.f);
            if (gr < M) v = *(const float4*)(A + (size_t)gr * K + k0 + a_c);
            As[a_c + 0][a_r] = v.x;
            As[a_c + 1][a_r] = v.y;
            As[a_c + 2][a_r] = v.z;
            As[a_c + 3][a_r] = v.w;
        }
        // load B tile (16x64)
        {
            int gc = col0 + b_c;
            const float* bp = B + (size_t)(k0 + b_r) * N + gc;
            float4 v;
            if (n4 && gc + 3 < N) {
                v = *(const float4*)bp;
            } else {
                v.x = (gc + 0 < N) ? bp[0] : 0.f;
                v.y = (gc + 1 < N) ? bp[1] : 0.f;
                v.z = (gc + 2 < N) ? bp[2] : 0.f;
                v.w = (gc + 3 < N) ? bp[3] : 0.f;
            }
            Bs[b_r][b_c + 0] = v.x;
            Bs[b_r][b_c + 1] = v.y;
            Bs[b_r][b_c + 2] = v.z;
            Bs[b_r][b_c + 3] = v.w;
        }
        __syncthreads();
        #pragma unroll
        for (int k = 0; k < 16; ++k) {
            float a0 = As[k][ty * 4 + 0];
            float a1 = As[k][ty * 4 + 1];
            float a2 = As[k][ty * 4 + 2];
            float a3 = As[k][ty * 4 + 3];
            float b0 = Bs[k][tx * 4 + 0];
            float b1 = Bs[k][tx * 4 + 1];
            float b2 = Bs[k][tx * 4 + 2];
            float b3 = Bs[k][tx * 4 + 3];
            acc[0][0] += a0 * b0; acc[0][1] += a0 * b1; acc[0][2] += a0 * b2; acc[0][3] += a0 * b3;
            acc[1][0] += a1 * b0; acc[1][1] += a1 * b1; acc[1][2] += a1 * b2; acc[1][3] += a1 * b3;
            acc[2][0] += a2 * b0; acc[2][1] += a2 * b1; acc[2][2] += a2 * b2; acc[2][3] += a2 * b3;
            acc[3][0] += a3 * b0; acc[3][1] += a3 * b1; acc[3][2] += a3 * b2; acc[3][3] += a3 * b3;
        }
        __syncthreads();
    }
    #pragma unroll
    for (int i = 0; i < 4; ++i) {
        int r = row0 + ty * 4 + i;
        if (r >= M) continue;
        #pragma unroll
        for (int j = 0; j < 4; ++j) {
            int c = col0 + tx * 4 + j;
            if (c >= N) continue;
            float v = acc[i][j];
            if (bias) v += bias[c];
            C[(size_t)r * N + c] = v;
        }
    }
}

// ------------- per-node attention halves: asrc[n,h], adst[n,h] --------------
__global__ __launch_bounds__(64) void attn_scores(
    const float* __restrict__ h, const float* __restrict__ a_src,
    const float* __restrict__ a_dst, float* __restrict__ asrc,
    float* __restrict__ adst, int C)
{
    int n = blockIdx.x;
    int head = blockIdx.y;
    int lane = threadIdx.x;
    const float* hp = h + (size_t)n * HH * C + head * C;
    const float* asp = a_src + head * C;
    const float* adp = a_dst + head * C;
    float s1 = 0.f, s2 = 0.f;
    for (int c = lane; c < C; c += 64) {
        float v = hp[c];
        s1 += v * asp[c];
        s2 += v * adp[c];
    }
    #pragma unroll
    for (int off = 32; off > 0; off >>= 1) {
        s1 += __shfl_down(s1, off, 64);
        s2 += __shfl_down(s2, off, 64);
    }
    if (lane == 0) {
        asrc[n * HH + head] = s1;
        adst[n * HH + head] = s2;
    }
}

// ---------------- CSR build: histogram, scan, scatter -----------------------
__global__ void edge_histogram(const int* __restrict__ ei, int* __restrict__ deg)
{
    int t = blockIdx.x * blockDim.x + threadIdx.x;
    if (t >= ET) return;
    int dst = (t < EE) ? ei[EE + t] : (t - EE);
    atomicAdd(&deg[dst], 1);
}

__global__ __launch_bounds__(1024) void scan_offsets(
    const int* __restrict__ deg, int* __restrict__ off, int* __restrict__ pos)
{
    __shared__ int wsum[16];
    __shared__ int carry_s;
    int tid = threadIdx.x;
    int lane = tid & 63, wid = tid >> 6;
    if (tid == 0) carry_s = 0;
    __syncthreads();
    for (int base = 0; base < NN; base += 1024) {
        int i = base + tid;
        int v = (i < NN) ? deg[i] : 0;
        int s = v;
        #pragma unroll
        for (int o = 1; o < 64; o <<= 1) {
            int t = __shfl_up(s, o, 64);
            if (lane >= o) s += t;
        }
        if (lane == 63) wsum[wid] = s;
        __syncthreads();
        if (wid == 0 && lane < 16) {
            int w = wsum[lane];
            #pragma unroll
            for (int o = 1; o < 16; o <<= 1) {
                int t = __shfl_up(w, o, 64);
                if (lane >= o) w += t;
            }
            wsum[lane] = w;
        }
        __syncthreads();
        int woff = (wid == 0) ? 0 : wsum[wid - 1];
        int carry = carry_s;
        int excl = carry + woff + s - v;
        if (i < NN) { off[i] = excl; pos[i] = excl; }
        __syncthreads();
        if (tid == 1023) carry_s = carry + wsum[15];
        __syncthreads();
    }
    if (tid == 0) off[NN] = carry_s;
}

__global__ void edge_scatter(const int* __restrict__ ei,
                             int* __restrict__ pos, int* __restrict__ csr_src)
{
    int t = blockIdx.x * blockDim.x + threadIdx.x;
    if (t >= ET) return;
    int src, dst;
    if (t < EE) { src = ei[t]; dst = ei[EE + t]; }
    else        { src = t - EE; dst = t - EE; }
    int p = atomicAdd(&pos[dst], 1);
    csr_src[p] = src;
}

// ---- fused per-node edge-softmax + aggregation + bias + ELU (no atomics) ---
// one wave per (node, head); C = 128 (2 ch/lane) or 64 (1 ch/lane)
__global__ __launch_bounds__(64) void aggregate(
    const float* __restrict__ h, const int* __restrict__ off,
    const int* __restrict__ csr_src, const float* __restrict__ asrc,
    const float* __restrict__ adst, const float* __restrict__ bias,
    float* __restrict__ out, int C)
{
    int n = blockIdx.x;
    int head = blockIdx.y;
    int lane = threadIdx.x;
    int start = off[n], end = off[n + 1];
    float adst_v = adst[n * HH + head];
    int HC = HH * C;
    float acc0 = 0.f, acc1 = 0.f, denom = 0.f;
    for (int j = start; j < end; ++j) {
        int s = csr_src[j];
        float e = asrc[s * HH + head] + adst_v;
        e = (e > 0.f) ? e : 0.2f * e;           // leaky_relu 0.2
        float ex = __expf(e);
        denom += ex;
        const float* hp = h + (size_t)s * HC + head * C;
        acc0 += ex * hp[lane];
        if (C == 128) acc1 += ex * hp[lane + 64];
    }
    float inv = 1.f / (denom + 1e-16f);
    const float* bp = bias + head * C;
    float* op = out + (size_t)n * HC + head * C;
    float v0 = acc0 * inv + bp[lane];
    v0 = (v0 > 0.f) ? v0 : expm1f(v0);          // ELU
    op[lane] = v0;
    if (C == 128) {
        float v1 = acc1 * inv + bp[lane + 64];
        v1 = (v1 > 0.f) ? v1 : expm1f(v1);
        op[lane + 64] = v1;
    }
}

extern "C" void kernel_launch(void* const* d_in, const int* in_sizes, int n_in,
                              void* d_out, int out_size, void* d_ws, size_t ws_size,
                              hipStream_t stream) {
    const float* x      = (const float*)d_in[0];
    const int*   ei     = (const int*)d_in[1];
    const float* W1     = (const float*)d_in[2];
    const float* a_src1 = (const float*)d_in[3];
    const float* a_dst1 = (const float*)d_in[4];
    const float* b1     = (const float*)d_in[5];
    const float* W2     = (const float*)d_in[6];
    const float* a_src2 = (const float*)d_in[7];
    const float* a_dst2 = (const float*)d_in[8];
    const float* b2     = (const float*)d_in[9];
    const float* Wf     = (const float*)d_in[10];
    const float* bf     = (const float*)d_in[11];
    float* out = (float*)d_out;

    // workspace layout
    float* h1   = (float*)d_ws;                      // 50000*512
    float* out1 = h1 + (size_t)NN * HH * CC1;        // 50000*512
    float* h2   = out1 + (size_t)NN * HH * CC1;      // 50000*256
    float* asrc = h2 + (size_t)NN * HH * CC2;        // 50000*4
    float* adst = asrc + (size_t)NN * HH;            // 50000*4
    int* deg     = (int*)(adst + (size_t)NN * HH);   // NN
    int* csr_off = deg + NN;                          // NN+1
    int* csr_pos = csr_off + NN + 1;                  // NN
    int* csr_src = csr_pos + NN;                      // ET
    float* out2 = h1;  // alias: h1 dead after GEMM2

    hipMemsetAsync(deg, 0, NN * sizeof(int), stream);

    // layer 1 GEMM: h1 = x @ W1   [50000,256]@[256,512]
    gemm_f32<<<dim3((NN + 63) / 64, 512 / 64), 256, 0, stream>>>(
        x, W1, nullptr, h1, NN, HH * CC1, FIN);

    // CSR build (used by both layers)
    edge_histogram<<<(ET + 255) / 256, 256, 0, stream>>>(ei, deg);
    scan_offsets<<<1, 1024, 0, stream>>>(deg, csr_off, csr_pos);
    edge_scatter<<<(ET + 255) / 256, 256, 0, stream>>>(ei, csr_pos, csr_src);

    // layer 1 attention + aggregation + bias + ELU
    attn_scores<<<dim3(NN, HH), 64, 0, stream>>>(h1, a_src1, a_dst1, asrc, adst, CC1);
    aggregate<<<dim3(NN, HH), 64, 0, stream>>>(h1, csr_off, csr_src, asrc, adst, b1, out1, CC1);

    // layer 2 GEMM: h2 = out1 @ W2   [50000,512]@[512,256]
    gemm_f32<<<dim3((NN + 63) / 64, 256 / 64), 256, 0, stream>>>(
        out1, W2, nullptr, h2, NN, HH * CC2, HH * CC1);

    attn_scores<<<dim3(NN, HH), 64, 0, stream>>>(h2, a_src2, a_dst2, asrc, adst, CC2);
    aggregate<<<dim3(NN, HH), 64, 0, stream>>>(h2, csr_off, csr_src, asrc, adst, b2, out2, CC2);

    // final: out = out2 @ Wf + bf   [50000,256]@[256,50]
    gemm_f32<<<dim3((NN + 63) / 64, (NCLS + 63) / 64), 256, 0, stream>>>(
        out2, Wf, bf, out, NN, NCLS, HH * CC2);
}

// Round 2
// 1087.997 us; speedup vs baseline: 1.1857x; 1.1857x over previous
//
#include <hip/hip_runtime.h>
#include <hip/hip_bf16.h>
#include <cmath>

// Problem constants
#define NN 50000
#define EE 800000
#define ET 850000   // EE + NN self loops
#define HH 4
#define CC1 128
#define CC2 64
#define FIN 256
#define NCLS 50

// ---------------- fp32 tiled GEMM (64x64) — used for the small final GEMM ---
__global__ __launch_bounds__(256) void gemm_f32(
    const float* __restrict__ A, const float* __restrict__ B,
    const float* __restrict__ bias, float* __restrict__ C,
    int M, int N, int K)
{
    __shared__ float As[16][64 + 4];
    __shared__ float Bs[16][64 + 4];
    int tid = threadIdx.x;
    int row0 = blockIdx.x * 64;
    int col0 = blockIdx.y * 64;
    int tx = tid & 15;
    int ty = tid >> 4;
    float acc[4][4] = {{0.f}};

    int a_r = tid >> 2;
    int a_c = (tid & 3) << 2;
    int b_r = tid >> 4;
    int b_c = (tid & 15) << 2;
    bool n4 = ((N & 3) == 0);

    for (int k0 = 0; k0 < K; k0 += 16) {
        {
            int gr = row0 + a_r;
            float4 v = make_float4(0.f, 0.f, 0.f, 0.f);
            if (gr < M) v = *(const float4*)(A + (size_t)gr * K + k0 + a_c);
            As[a_c + 0][a_r] = v.x;
            As[a_c + 1][a_r] = v.y;
            As[a_c + 2][a_r] = v.z;
            As[a_c + 3][a_r] = v.w;
        }
        {
            int gc = col0 + b_c;
            const float* bp = B + (size_t)(k0 + b_r) * N + gc;
            float4 v;
            if (n4 && gc + 3 < N) {
                v = *(const float4*)bp;
            } else {
                v.x = (gc + 0 < N) ? bp[0] : 0.f;
                v.y = (gc + 1 < N) ? bp[1] : 0.f;
                v.z = (gc + 2 < N) ? bp[2] : 0.f;
                v.w = (gc + 3 < N) ? bp[3] : 0.f;
            }
            Bs[b_r][b_c + 0] = v.x;
            Bs[b_r][b_c + 1] = v.y;
            Bs[b_r][b_c + 2] = v.z;
            Bs[b_r][b_c + 3] = v.w;
        }
        __syncthreads();
        #pragma unroll
        for (int k = 0; k < 16; ++k) {
            float a0 = As[k][ty * 4 + 0];
            float a1 = As[k][ty * 4 + 1];
            float a2 = As[k][ty * 4 + 2];
            float a3 = As[k][ty * 4 + 3];
            float b0 = Bs[k][tx * 4 + 0];
            float b1 = Bs[k][tx * 4 + 1];
            float b2 = Bs[k][tx * 4 + 2];
            float b3 = Bs[k][tx * 4 + 3];
            acc[0][0] += a0 * b0; acc[0][1] += a0 * b1; acc[0][2] += a0 * b2; acc[0][3] += a0 * b3;
            acc[1][0] += a1 * b0; acc[1][1] += a1 * b1; acc[1][2] += a1 * b2; acc[1][3] += a1 * b3;
            acc[2][0] += a2 * b0; acc[2][1] += a2 * b1; acc[2][2] += a2 * b2; acc[2][3] += a2 * b3;
            acc[3][0] += a3 * b0; acc[3][1] += a3 * b1; acc[3][2] += a3 * b2; acc[3][3] += a3 * b3;
        }
        __syncthreads();
    }
    #pragma unroll
    for (int i = 0; i < 4; ++i) {
        int r = row0 + ty * 4 + i;
        if (r >= M) continue;
        #pragma unroll
        for (int j = 0; j < 4; ++j) {
            int c = col0 + tx * 4 + j;
            if (c >= N) continue;
            float v = acc[i][j];
            if (bias) v += bias[c];
            C[(size_t)r * N + c] = v;
        }
    }
}

// ---------------- fp32 tiled GEMM (128x128, 8x8/thread) ---------------------
// Requires N % 128 == 0, K % 16 == 0. M guarded.
// LDS stride 136 keeps float4 alignment (136*4=544, mult of 16).
__global__ __launch_bounds__(256) void gemm_f32_128(
    const float* __restrict__ A, const float* __restrict__ B,
    float* __restrict__ C, int M, int N, int K)
{
    __shared__ float As[16][136];
    __shared__ float Bs[16][136];
    int tid = threadIdx.x;
    int tx = tid & 15;        // 0..15 col group
    int ty = tid >> 4;        // 0..15 row group
    int row0 = blockIdx.x * 128;
    int col0 = blockIdx.y * 128;

    float acc[8][8] = {{0.f}};

    // staging indices
    int ar = tid >> 1;           // 0..127 row within A tile
    int ak = (tid & 1) * 8;      // 0 or 8 (k half)
    int bk = tid >> 4;           // 0..15 k within B tile
    int bc = tx * 4;             // 0..60 col quarter

    for (int k0 = 0; k0 < K; k0 += 16) {
        // global loads into regs
        float4 a0 = make_float4(0.f, 0.f, 0.f, 0.f);
        float4 a1 = make_float4(0.f, 0.f, 0.f, 0.f);
        int gr = row0 + ar;
        if (gr < M) {
            const float* ap = A + (size_t)gr * K + k0 + ak;
            a0 = *(const float4*)ap;
            a1 = *(const float4*)(ap + 4);
        }
        const float* bp = B + (size_t)(k0 + bk) * N + col0;
        float4 b0 = *(const float4*)(bp + bc);
        float4 b1 = *(const float4*)(bp + bc + 64);

        __syncthreads();   // previous iteration's LDS reads done
        // A transposed into As[k][row]
        As[ak + 0][ar] = a0.x;
        As[ak + 1][ar] = a0.y;
        As[ak + 2][ar] = a0.z;
        As[ak + 3][ar] = a0.w;
        As[ak + 4][ar] = a1.x;
        As[ak + 5][ar] = a1.y;
        As[ak + 6][ar] = a1.z;
        As[ak + 7][ar] = a1.w;
        *(float4*)&Bs[bk][bc]      = b0;
        *(float4*)&Bs[bk][bc + 64] = b1;
        __syncthreads();

        #pragma unroll
        for (int k = 0; k < 16; ++k) {
            float a[8], b[8];
            *(float4*)(a + 0) = *(const float4*)&As[k][ty * 4];
            *(float4*)(a + 4) = *(const float4*)&As[k][ty * 4 + 64];
            *(float4*)(b + 0) = *(const float4*)&Bs[k][tx * 4];
            *(float4*)(b + 4) = *(const float4*)&Bs[k][tx * 4 + 64];
            #pragma unroll
            for (int i = 0; i < 8; ++i)
                #pragma unroll
                for (int j = 0; j < 8; ++j)
                    acc[i][j] += a[i] * b[j];
        }
    }

    // store: rows ty*4..+3 and 64+ty*4..+3; cols tx*4..+3 and 64+tx*4..+3
    #pragma unroll
    for (int ih = 0; ih < 2; ++ih) {
        #pragma unroll
        for (int i = 0; i < 4; ++i) {
            int r = row0 + ih * 64 + ty * 4 + i;
            if (r >= M) continue;
            float* cp = C + (size_t)r * N + col0;
            *(float4*)(cp + tx * 4)      = *(float4*)&acc[ih * 4 + i][0];
            *(float4*)(cp + tx * 4 + 64) = *(float4*)&acc[ih * 4 + i][4];
        }
    }
}

// ------------- per-node attention halves: asrc[n,h], adst[n,h] --------------
__global__ __launch_bounds__(64) void attn_scores(
    const float* __restrict__ h, const float* __restrict__ a_src,
    const float* __restrict__ a_dst, float* __restrict__ asrc,
    float* __restrict__ adst, int C)
{
    int n = blockIdx.x;
    int head = blockIdx.y;
    int lane = threadIdx.x;
    const float* hp = h + (size_t)n * HH * C + head * C;
    const float* asp = a_src + head * C;
    const float* adp = a_dst + head * C;
    float s1 = 0.f, s2 = 0.f;
    for (int c = lane; c < C; c += 64) {
        float v = hp[c];
        s1 += v * asp[c];
        s2 += v * adp[c];
    }
    #pragma unroll
    for (int off = 32; off > 0; off >>= 1) {
        s1 += __shfl_down(s1, off, 64);
        s2 += __shfl_down(s2, off, 64);
    }
    if (lane == 0) {
        asrc[n * HH + head] = s1;
        adst[n * HH + head] = s2;
    }
}

// ---------------- CSR build: histogram, scan, scatter -----------------------
__global__ void edge_histogram(const int* __restrict__ ei, int* __restrict__ deg)
{
    int t = blockIdx.x * blockDim.x + threadIdx.x;
    if (t >= ET) return;
    int dst = (t < EE) ? ei[EE + t] : (t - EE);
    atomicAdd(&deg[dst], 1);
}

__global__ __launch_bounds__(1024) void scan_offsets(
    const int* __restrict__ deg, int* __restrict__ off, int* __restrict__ pos)
{
    __shared__ int wsum[16];
    __shared__ int carry_s;
    int tid = threadIdx.x;
    int lane = tid & 63, wid = tid >> 6;
    if (tid == 0) carry_s = 0;
    __syncthreads();
    for (int base = 0; base < NN; base += 1024) {
        int i = base + tid;
        int v = (i < NN) ? deg[i] : 0;
        int s = v;
        #pragma unroll
        for (int o = 1; o < 64; o <<= 1) {
            int t = __shfl_up(s, o, 64);
            if (lane >= o) s += t;
        }
        if (lane == 63) wsum[wid] = s;
        __syncthreads();
        if (wid == 0 && lane < 16) {
            int w = wsum[lane];
            #pragma unroll
            for (int o = 1; o < 16; o <<= 1) {
                int t = __shfl_up(w, o, 64);
                if (lane >= o) w += t;
            }
            wsum[lane] = w;
        }
        __syncthreads();
        int woff = (wid == 0) ? 0 : wsum[wid - 1];
        int carry = carry_s;
        int excl = carry + woff + s - v;
        if (i < NN) { off[i] = excl; pos[i] = excl; }
        __syncthreads();
        if (tid == 1023) carry_s = carry + wsum[15];
        __syncthreads();
    }
    if (tid == 0) off[NN] = carry_s;
}

__global__ void edge_scatter(const int* __restrict__ ei,
                             int* __restrict__ pos, int* __restrict__ csr_src)
{
    int t = blockIdx.x * blockDim.x + threadIdx.x;
    if (t >= ET) return;
    int src, dst;
    if (t < EE) { src = ei[t]; dst = ei[EE + t]; }
    else        { src = t - EE; dst = t - EE; }
    int p = atomicAdd(&pos[dst], 1);
    csr_src[p] = src;
}

// ---- fused per-node edge-softmax + aggregation + bias + ELU (no atomics) ---
// one wave per (node, head); unroll 4 edges for MLP.
template<int C>
__global__ __launch_bounds__(64) void aggregate2(
    const float* __restrict__ h, const int* __restrict__ off,
    const int* __restrict__ csr_src, const float* __restrict__ asrc,
    const float* __restrict__ adst, const float* __restrict__ bias,
    float* __restrict__ out)
{
    constexpr int HC = HH * C;
    int n = blockIdx.x;
    int head = blockIdx.y;
    int lane = threadIdx.x;
    int start = off[n], end = off[n + 1];
    float adst_v = adst[n * HH + head];
    float accx = 0.f, accy = 0.f, denom = 0.f;

    int j = start;
    for (; j + 4 <= end; j += 4) {
        int s0 = csr_src[j + 0];
        int s1 = csr_src[j + 1];
        int s2 = csr_src[j + 2];
        int s3 = csr_src[j + 3];
        float e0 = asrc[s0 * HH + head];
        float e1 = asrc[s1 * HH + head];
        float e2 = asrc[s2 * HH + head];
        float e3 = asrc[s3 * HH + head];
        float2 v0, v1, v2, v3;
        if (C == 128) {
            v0 = *(const float2*)(h + (size_t)s0 * HC + head * C + 2 * lane);
            v1 = *(const float2*)(h + (size_t)s1 * HC + head * C + 2 * lane);
            v2 = *(const float2*)(h + (size_t)s2 * HC + head * C + 2 * lane);
            v3 = *(const float2*)(h + (size_t)s3 * HC + head * C + 2 * lane);
        } else {
            v0.x = h[(size_t)s0 * HC + head * C + lane]; v0.y = 0.f;
            v1.x = h[(size_t)s1 * HC + head * C + lane]; v1.y = 0.f;
            v2.x = h[(size_t)s2 * HC + head * C + lane]; v2.y = 0.f;
            v3.x = h[(size_t)s3 * HC + head * C + lane]; v3.y = 0.f;
        }
        e0 += adst_v; e1 += adst_v; e2 += adst_v; e3 += adst_v;
        e0 = (e0 > 0.f) ? e0 : 0.2f * e0;
        e1 = (e1 > 0.f) ? e1 : 0.2f * e1;
        e2 = (e2 > 0.f) ? e2 : 0.2f * e2;
        e3 = (e3 > 0.f) ? e3 : 0.2f * e3;
        float x0 = __expf(e0), x1 = __expf(e1), x2 = __expf(e2), x3 = __expf(e3);
        denom += (x0 + x1) + (x2 + x3);
        accx += x0 * v0.x + x1 * v1.x + x2 * v2.x + x3 * v3.x;
        if (C == 128) accy += x0 * v0.y + x1 * v1.y + x2 * v2.y + x3 * v3.y;
    }
    for (; j < end; ++j) {
        int s = csr_src[j];
        float e = asrc[s * HH + head] + adst_v;
        e = (e > 0.f) ? e : 0.2f * e;
        float ex = __expf(e);
        denom += ex;
        const float* hp = h + (size_t)s * HC + head * C;
        if (C == 128) {
            float2 v = *(const float2*)(hp + 2 * lane);
            accx += ex * v.x;
            accy += ex * v.y;
        } else {
            accx += ex * hp[lane];
        }
    }

    float inv = 1.f / (denom + 1e-16f);
    const float* bp = bias + head * C;
    float* op = out + (size_t)n * HC + head * C;
    if (C == 128) {
        float u0 = accx * inv + bp[2 * lane];
        float u1 = accy * inv + bp[2 * lane + 1];
        u0 = (u0 > 0.f) ? u0 : expm1f(u0);
        u1 = (u1 > 0.f) ? u1 : expm1f(u1);
        op[2 * lane]     = u0;
        op[2 * lane + 1] = u1;
    } else {
        float u0 = accx * inv + bp[lane];
        u0 = (u0 > 0.f) ? u0 : expm1f(u0);
        op[lane] = u0;
    }
}

extern "C" void kernel_launch(void* const* d_in, const int* in_sizes, int n_in,
                              void* d_out, int out_size, void* d_ws, size_t ws_size,
                              hipStream_t stream) {
    const float* x      = (const float*)d_in[0];
    const int*   ei     = (const int*)d_in[1];
    const float* W1     = (const float*)d_in[2];
    const float* a_src1 = (const float*)d_in[3];
    const float* a_dst1 = (const float*)d_in[4];
    const float* b1     = (const float*)d_in[5];
    const float* W2     = (const float*)d_in[6];
    const float* a_src2 = (const float*)d_in[7];
    const float* a_dst2 = (const float*)d_in[8];
    const float* b2     = (const float*)d_in[9];
    const float* Wf     = (const float*)d_in[10];
    const float* bf     = (const float*)d_in[11];
    float* out = (float*)d_out;

    // workspace layout
    float* h1   = (float*)d_ws;                      // 50000*512
    float* out1 = h1 + (size_t)NN * HH * CC1;        // 50000*512
    float* h2   = out1 + (size_t)NN * HH * CC1;      // 50000*256
    float* asrc = h2 + (size_t)NN * HH * CC2;        // 50000*4
    float* adst = asrc + (size_t)NN * HH;            // 50000*4
    int* deg     = (int*)(adst + (size_t)NN * HH);   // NN
    int* csr_off = deg + NN;                          // NN+1
    int* csr_pos = csr_off + NN + 1;                  // NN
    int* csr_src = csr_pos + NN;                      // ET
    float* out2 = h1;  // alias: h1 dead after GEMM2

    hipMemsetAsync(deg, 0, NN * sizeof(int), stream);

    // layer 1 GEMM: h1 = x @ W1   [50000,256]@[256,512]
    gemm_f32_128<<<dim3((NN + 127) / 128, 512 / 128), 256, 0, stream>>>(
        x, W1, h1, NN, HH * CC1, FIN);

    // CSR build (used by both layers)
    edge_histogram<<<(ET + 255) / 256, 256, 0, stream>>>(ei, deg);
    scan_offsets<<<1, 1024, 0, stream>>>(deg, csr_off, csr_pos);
    edge_scatter<<<(ET + 255) / 256, 256, 0, stream>>>(ei, csr_pos, csr_src);

    // layer 1 attention + aggregation + bias + ELU
    attn_scores<<<dim3(NN, HH), 64, 0, stream>>>(h1, a_src1, a_dst1, asrc, adst, CC1);
    aggregate2<CC1><<<dim3(NN, HH), 64, 0, stream>>>(h1, csr_off, csr_src, asrc, adst, b1, out1);

    // layer 2 GEMM: h2 = out1 @ W2   [50000,512]@[512,256]
    gemm_f32_128<<<dim3((NN + 127) / 128, 256 / 128), 256, 0, stream>>>(
        out1, W2, h2, NN, HH * CC2, HH * CC1);

    attn_scores<<<dim3(NN, HH), 64, 0, stream>>>(h2, a_src2, a_dst2, asrc, adst, CC2);
    aggregate2<CC2><<<dim3(NN, HH), 64, 0, stream>>>(h2, csr_off, csr_src, asrc, adst, b2, out2);

    // final: out = out2 @ Wf + bf   [50000,256]@[256,50]
    gemm_f32<<<dim3((NN + 63) / 64, (NCLS + 63) / 64), 256, 0, stream>>>(
        out2, Wf, bf, out, NN, NCLS, HH * CC2);
}

// Round 3
// 727.720 us; speedup vs baseline: 1.7727x; 1.4951x over previous
//
#include <hip/hip_runtime.h>
#include <hip/hip_bf16.h>
#include <cmath>

// Problem constants
#define NN 50000
#define EE 800000
#define ET 850000   // EE + NN self loops
#define HH 4
#define CC1 128
#define CC2 64
#define FIN 256
#define NCLS 50

typedef __attribute__((ext_vector_type(8))) short   short8;
typedef __attribute__((ext_vector_type(8))) unsigned short ushort8;
typedef __attribute__((ext_vector_type(4))) float   floatx4;

__device__ __forceinline__ unsigned short f2bf(float f) {
    union { float f; unsigned int u; } x; x.f = f;
    unsigned int lsb = (x.u >> 16) & 1u;
    x.u += 0x7fffu + lsb;          // round-to-nearest-even
    return (unsigned short)(x.u >> 16);
}
__device__ __forceinline__ float bf2f(unsigned short b) {
    union { unsigned int u; float f; } x; x.u = ((unsigned int)b) << 16;
    return x.f;
}

// ---------------- cast fp32 -> bf16 (4 elems/thread) ------------------------
__global__ __launch_bounds__(256) void cast_bf16(
    const float* __restrict__ in, unsigned short* __restrict__ out, int n4)
{
    int t = blockIdx.x * blockDim.x + threadIdx.x;
    if (t >= n4) return;
    float4 v = *(const float4*)(in + 4 * (size_t)t);
    unsigned short r0 = f2bf(v.x), r1 = f2bf(v.y), r2 = f2bf(v.z), r3 = f2bf(v.w);
    unsigned int lo = (unsigned int)r0 | ((unsigned int)r1 << 16);
    unsigned int hi = (unsigned int)r2 | ((unsigned int)r3 << 16);
    *(uint2*)(out + 4 * (size_t)t) = make_uint2(lo, hi);
}

// ---------------- transpose + cast: W[K,N] f32 -> Wt[N,K] bf16 --------------
__global__ __launch_bounds__(256) void transpose_cast(
    const float* __restrict__ W, unsigned short* __restrict__ Wt, int K, int N)
{
    int t = blockIdx.x * blockDim.x + threadIdx.x;
    if (t >= K * N) return;
    int n = t / K, k = t - n * K;
    Wt[t] = f2bf(W[(size_t)k * N + n]);
}

// ---------------- bf16 MFMA GEMM: C[M,N] = A[M,K] @ Bt[N,K]^T ---------------
// 128x128 tile, 4 waves, 64x64/wave as 4x4 mfma 16x16x32 tiles. Output bf16.
// Requires N % 128 == 0, K % 32 == 0. M guarded.
// LDS row stride 40 bf16 (80 B): frag reads/writes land 8-per-bank (uniform).
__global__ __launch_bounds__(256) void gemm_bf16(
    const unsigned short* __restrict__ A,   // [M,K] bf16
    const unsigned short* __restrict__ Bt,  // [N,K] bf16
    unsigned short* __restrict__ C,         // [M,N] bf16
    int M, int N, int K)
{
    __shared__ unsigned short As[128 * 40];
    __shared__ unsigned short Bs[128 * 40];
    int tid  = threadIdx.x;
    int wave = tid >> 6;
    int lane = tid & 63;
    int wm = (wave >> 1) * 64;
    int wn = (wave & 1) * 64;
    int row0 = blockIdx.x * 128;
    int col0 = blockIdx.y * 128;

    int lm = lane & 15;       // m (or n) within 16x16 tile
    int lq = lane >> 4;       // quad -> k-offset lq*8, and C-row group
    int kq = lq * 8;

    floatx4 acc[4][4] = {};

    int sr = tid >> 1;            // 0..127 row (A) / col (Bt) within tile
    int sk = (tid & 1) * 16;      // k half: 0 or 16

    for (int k0 = 0; k0 < K; k0 += 32) {
        ushort8 a0 = {0,0,0,0,0,0,0,0}, a1 = {0,0,0,0,0,0,0,0};
        int gr = row0 + sr;
        if (gr < M) {
            const unsigned short* ap = A + (size_t)gr * K + k0 + sk;
            a0 = *(const ushort8*)ap;
            a1 = *(const ushort8*)(ap + 8);
        }
        const unsigned short* bp = Bt + (size_t)(col0 + sr) * K + k0 + sk;
        ushort8 b0 = *(const ushort8*)bp;
        ushort8 b1 = *(const ushort8*)(bp + 8);

        __syncthreads();   // previous iter's LDS reads done
        *(ushort8*)&As[sr * 40 + sk]     = a0;
        *(ushort8*)&As[sr * 40 + sk + 8] = a1;
        *(ushort8*)&Bs[sr * 40 + sk]     = b0;
        *(ushort8*)&Bs[sr * 40 + sk + 8] = b1;
        __syncthreads();

        short8 af[4], bf_[4];
        #pragma unroll
        for (int mt = 0; mt < 4; ++mt)
            af[mt] = *(const short8*)&As[(wm + mt * 16 + lm) * 40 + kq];
        #pragma unroll
        for (int nt = 0; nt < 4; ++nt)
            bf_[nt] = *(const short8*)&Bs[(wn + nt * 16 + lm) * 40 + kq];
        #pragma unroll
        for (int mt = 0; mt < 4; ++mt)
            #pragma unroll
            for (int nt = 0; nt < 4; ++nt)
                acc[mt][nt] = __builtin_amdgcn_mfma_f32_16x16x32_bf16(
                    af[mt], bf_[nt], acc[mt][nt], 0, 0, 0);
    }

    // C/D layout: col = lane&15, row = (lane>>4)*4 + reg
    #pragma unroll
    for (int mt = 0; mt < 4; ++mt) {
        int rbase = row0 + wm + mt * 16 + lq * 4;
        #pragma unroll
        for (int nt = 0; nt < 4; ++nt) {
            int c = col0 + wn + nt * 16 + lm;
            #pragma unroll
            for (int r = 0; r < 4; ++r) {
                int gr = rbase + r;
                if (gr < M) C[(size_t)gr * N + c] = f2bf(acc[mt][nt][r]);
            }
        }
    }
}

// ------------- per-node attention halves from bf16 h ------------------------
__global__ __launch_bounds__(64) void attn_scores_bf16(
    const unsigned short* __restrict__ h, const float* __restrict__ a_src,
    const float* __restrict__ a_dst, float* __restrict__ asrc,
    float* __restrict__ adst, int C)
{
    int n = blockIdx.x;
    int head = blockIdx.y;
    int lane = threadIdx.x;
    const unsigned short* hp = h + (size_t)n * HH * C + head * C;
    const float* asp = a_src + head * C;
    const float* adp = a_dst + head * C;
    float s1 = 0.f, s2 = 0.f;
    for (int c = lane; c < C; c += 64) {
        float v = bf2f(hp[c]);
        s1 += v * asp[c];
        s2 += v * adp[c];
    }
    #pragma unroll
    for (int off = 32; off > 0; off >>= 1) {
        s1 += __shfl_down(s1, off, 64);
        s2 += __shfl_down(s2, off, 64);
    }
    if (lane == 0) {
        asrc[n * HH + head] = s1;
        adst[n * HH + head] = s2;
    }
}

// ---------------- CSR build: histogram, scan, scatter -----------------------
__global__ void edge_histogram(const int* __restrict__ ei, int* __restrict__ deg)
{
    int t = blockIdx.x * blockDim.x + threadIdx.x;
    if (t >= ET) return;
    int dst = (t < EE) ? ei[EE + t] : (t - EE);
    atomicAdd(&deg[dst], 1);
}

__global__ __launch_bounds__(1024) void scan_offsets(
    const int* __restrict__ deg, int* __restrict__ off, int* __restrict__ pos)
{
    __shared__ int wsum[16];
    __shared__ int carry_s;
    int tid = threadIdx.x;
    int lane = tid & 63, wid = tid >> 6;
    if (tid == 0) carry_s = 0;
    __syncthreads();
    for (int base = 0; base < NN; base += 1024) {
        int i = base + tid;
        int v = (i < NN) ? deg[i] : 0;
        int s = v;
        #pragma unroll
        for (int o = 1; o < 64; o <<= 1) {
            int t = __shfl_up(s, o, 64);
            if (lane >= o) s += t;
        }
        if (lane == 63) wsum[wid] = s;
        __syncthreads();
        if (wid == 0 && lane < 16) {
            int w = wsum[lane];
            #pragma unroll
            for (int o = 1; o < 16; o <<= 1) {
                int t = __shfl_up(w, o, 64);
                if (lane >= o) w += t;
            }
            wsum[lane] = w;
        }
        __syncthreads();
        int woff = (wid == 0) ? 0 : wsum[wid - 1];
        int carry = carry_s;
        int excl = carry + woff + s - v;
        if (i < NN) { off[i] = excl; pos[i] = excl; }
        __syncthreads();
        if (tid == 1023) carry_s = carry + wsum[15];
        __syncthreads();
    }
    if (tid == 0) off[NN] = carry_s;
}

__global__ void edge_scatter(const int* __restrict__ ei,
                             int* __restrict__ pos, int* __restrict__ csr_src)
{
    int t = blockIdx.x * blockDim.x + threadIdx.x;
    if (t >= ET) return;
    int src, dst;
    if (t < EE) { src = ei[t]; dst = ei[EE + t]; }
    else        { src = t - EE; dst = t - EE; }
    int p = atomicAdd(&pos[dst], 1);
    csr_src[p] = src;
}

// ---- fused per-node edge-softmax + aggregation + bias + ELU (bf16 h) -------
// one wave per (node, head); 4-edge unroll for MLP.
// C=128: lane reads ushort2 (1 dword) per edge. OUT_BF16 selects output type.
template<int C, bool OUT_BF16>
__global__ __launch_bounds__(64) void aggregate_bf16(
    const unsigned short* __restrict__ h, const int* __restrict__ off,
    const int* __restrict__ csr_src, const float* __restrict__ asrc,
    const float* __restrict__ adst, const float* __restrict__ bias,
    void* __restrict__ out_v)
{
    constexpr int HC = HH * C;
    int n = blockIdx.x;
    int head = blockIdx.y;
    int lane = threadIdx.x;
    int start = off[n], end = off[n + 1];
    float adst_v = adst[n * HH + head];
    float accx = 0.f, accy = 0.f, denom = 0.f;

    int j = start;
    for (; j + 4 <= end; j += 4) {
        int s0 = csr_src[j + 0];
        int s1 = csr_src[j + 1];
        int s2 = csr_src[j + 2];
        int s3 = csr_src[j + 3];
        float e0 = asrc[s0 * HH + head];
        float e1 = asrc[s1 * HH + head];
        float e2 = asrc[s2 * HH + head];
        float e3 = asrc[s3 * HH + head];
        float v0x, v0y = 0.f, v1x, v1y = 0.f, v2x, v2y = 0.f, v3x, v3y = 0.f;
        if (C == 128) {
            unsigned int u0 = *(const unsigned int*)(h + (size_t)s0 * HC + head * C + 2 * lane);
            unsigned int u1 = *(const unsigned int*)(h + (size_t)s1 * HC + head * C + 2 * lane);
            unsigned int u2 = *(const unsigned int*)(h + (size_t)s2 * HC + head * C + 2 * lane);
            unsigned int u3 = *(const unsigned int*)(h + (size_t)s3 * HC + head * C + 2 * lane);
            union { unsigned int u; float f; } c0, c1;
            c0.u = u0 << 16; v0x = c0.f; c1.u = u0 & 0xffff0000u; v0y = c1.f;
            c0.u = u1 << 16; v1x = c0.f; c1.u = u1 & 0xffff0000u; v1y = c1.f;
            c0.u = u2 << 16; v2x = c0.f; c1.u = u2 & 0xffff0000u; v2y = c1.f;
            c0.u = u3 << 16; v3x = c0.f; c1.u = u3 & 0xffff0000u; v3y = c1.f;
        } else {
            v0x = bf2f(h[(size_t)s0 * HC + head * C + lane]);
            v1x = bf2f(h[(size_t)s1 * HC + head * C + lane]);
            v2x = bf2f(h[(size_t)s2 * HC + head * C + lane]);
            v3x = bf2f(h[(size_t)s3 * HC + head * C + lane]);
        }
        e0 += adst_v; e1 += adst_v; e2 += adst_v; e3 += adst_v;
        e0 = (e0 > 0.f) ? e0 : 0.2f * e0;
        e1 = (e1 > 0.f) ? e1 : 0.2f * e1;
        e2 = (e2 > 0.f) ? e2 : 0.2f * e2;
        e3 = (e3 > 0.f) ? e3 : 0.2f * e3;
        float x0 = __expf(e0), x1 = __expf(e1), x2 = __expf(e2), x3 = __expf(e3);
        denom += (x0 + x1) + (x2 + x3);
        accx += x0 * v0x + x1 * v1x + x2 * v2x + x3 * v3x;
        if (C == 128) accy += x0 * v0y + x1 * v1y + x2 * v2y + x3 * v3y;
    }
    for (; j < end; ++j) {
        int s = csr_src[j];
        float e = asrc[s * HH + head] + adst_v;
        e = (e > 0.f) ? e : 0.2f * e;
        float ex = __expf(e);
        denom += ex;
        if (C == 128) {
            unsigned int u = *(const unsigned int*)(h + (size_t)s * HC + head * C + 2 * lane);
            union { unsigned int uu; float f; } c0, c1;
            c0.uu = u << 16; c1.uu = u & 0xffff0000u;
            accx += ex * c0.f;
            accy += ex * c1.f;
        } else {
            accx += ex * bf2f(h[(size_t)s * HC + head * C + lane]);
        }
    }

    float inv = 1.f / (denom + 1e-16f);
    const float* bp = bias + head * C;
    if (C == 128) {
        float u0 = accx * inv + bp[2 * lane];
        float u1 = accy * inv + bp[2 * lane + 1];
        u0 = (u0 > 0.f) ? u0 : expm1f(u0);
        u1 = (u1 > 0.f) ? u1 : expm1f(u1);
        if (OUT_BF16) {
            unsigned short* op = (unsigned short*)out_v + (size_t)n * HC + head * C;
            unsigned int packed = (unsigned int)f2bf(u0) | ((unsigned int)f2bf(u1) << 16);
            *(unsigned int*)(op + 2 * lane) = packed;
        } else {
            float* op = (float*)out_v + (size_t)n * HC + head * C;
            op[2 * lane] = u0;
            op[2 * lane + 1] = u1;
        }
    } else {
        float u0 = accx * inv + bp[lane];
        u0 = (u0 > 0.f) ? u0 : expm1f(u0);
        if (OUT_BF16) {
            unsigned short* op = (unsigned short*)out_v + (size_t)n * HC + head * C;
            op[lane] = f2bf(u0);
        } else {
            float* op = (float*)out_v + (size_t)n * HC + head * C;
            op[lane] = u0;
        }
    }
}

// ---------------- fp32 tiled GEMM (64x64) — final classifier layer ----------
__global__ __launch_bounds__(256) void gemm_f32(
    const float* __restrict__ A, const float* __restrict__ B,
    const float* __restrict__ bias, float* __restrict__ C,
    int M, int N, int K)
{
    __shared__ float As[16][64 + 4];
    __shared__ float Bs[16][64 + 4];
    int tid = threadIdx.x;
    int row0 = blockIdx.x * 64;
    int col0 = blockIdx.y * 64;
    int tx = tid & 15;
    int ty = tid >> 4;
    float acc[4][4] = {{0.f}};

    int a_r = tid >> 2;
    int a_c = (tid & 3) << 2;
    int b_r = tid >> 4;
    int b_c = (tid & 15) << 2;
    bool n4 = ((N & 3) == 0);

    for (int k0 = 0; k0 < K; k0 += 16) {
        {
            int gr = row0 + a_r;
            float4 v = make_float4(0.f, 0.f, 0.f, 0.f);
            if (gr < M) v = *(const float4*)(A + (size_t)gr * K + k0 + a_c);
            As[a_c + 0][a_r] = v.x;
            As[a_c + 1][a_r] = v.y;
            As[a_c + 2][a_r] = v.z;
            As[a_c + 3][a_r] = v.w;
        }
        {
            int gc = col0 + b_c;
            const float* bp = B + (size_t)(k0 + b_r) * N + gc;
            float4 v;
            if (n4 && gc + 3 < N) {
                v = *(const float4*)bp;
            } else {
                v.x = (gc + 0 < N) ? bp[0] : 0.f;
                v.y = (gc + 1 < N) ? bp[1] : 0.f;
                v.z = (gc + 2 < N) ? bp[2] : 0.f;
                v.w = (gc + 3 < N) ? bp[3] : 0.f;
            }
            Bs[b_r][b_c + 0] = v.x;
            Bs[b_r][b_c + 1] = v.y;
            Bs[b_r][b_c + 2] = v.z;
            Bs[b_r][b_c + 3] = v.w;
        }
        __syncthreads();
        #pragma unroll
        for (int k = 0; k < 16; ++k) {
            float a0 = As[k][ty * 4 + 0];
            float a1 = As[k][ty * 4 + 1];
            float a2 = As[k][ty * 4 + 2];
            float a3 = As[k][ty * 4 + 3];
            float b0 = Bs[k][tx * 4 + 0];
            float b1 = Bs[k][tx * 4 + 1];
            float b2 = Bs[k][tx * 4 + 2];
            float b3 = Bs[k][tx * 4 + 3];
            acc[0][0] += a0 * b0; acc[0][1] += a0 * b1; acc[0][2] += a0 * b2; acc[0][3] += a0 * b3;
            acc[1][0] += a1 * b0; acc[1][1] += a1 * b1; acc[1][2] += a1 * b2; acc[1][3] += a1 * b3;
            acc[2][0] += a2 * b0; acc[2][1] += a2 * b1; acc[2][2] += a2 * b2; acc[2][3] += a2 * b3;
            acc[3][0] += a3 * b0; acc[3][1] += a3 * b1; acc[3][2] += a3 * b2; acc[3][3] += a3 * b3;
        }
        __syncthreads();
    }
    #pragma unroll
    for (int i = 0; i < 4; ++i) {
        int r = row0 + ty * 4 + i;
        if (r >= M) continue;
        #pragma unroll
        for (int j = 0; j < 4; ++j) {
            int c = col0 + tx * 4 + j;
            if (c >= N) continue;
            float v = acc[i][j];
            if (bias) v += bias[c];
            C[(size_t)r * N + c] = v;
        }
    }
}

extern "C" void kernel_launch(void* const* d_in, const int* in_sizes, int n_in,
                              void* d_out, int out_size, void* d_ws, size_t ws_size,
                              hipStream_t stream) {
    const float* x      = (const float*)d_in[0];
    const int*   ei     = (const int*)d_in[1];
    const float* W1     = (const float*)d_in[2];
    const float* a_src1 = (const float*)d_in[3];
    const float* a_dst1 = (const float*)d_in[4];
    const float* b1     = (const float*)d_in[5];
    const float* W2     = (const float*)d_in[6];
    const float* a_src2 = (const float*)d_in[7];
    const float* a_dst2 = (const float*)d_in[8];
    const float* b2     = (const float*)d_in[9];
    const float* Wf     = (const float*)d_in[10];
    const float* bf     = (const float*)d_in[11];
    float* out = (float*)d_out;

    // workspace layout (bytes, all 16B-aligned)
    char* p = (char*)d_ws;
    unsigned short* xb    = (unsigned short*)p; p += (size_t)NN * FIN * 2;        // 25.6 MB
    unsigned short* h1b   = (unsigned short*)p; p += (size_t)NN * HH * CC1 * 2;   // 51.2 MB
    unsigned short* out1b = (unsigned short*)p; p += (size_t)NN * HH * CC1 * 2;   // 51.2 MB
    unsigned short* h2b   = (unsigned short*)p; p += (size_t)NN * HH * CC2 * 2;   // 25.6 MB
    float* out2           = (float*)p;          p += (size_t)NN * HH * CC2 * 4;   // 51.2 MB
    unsigned short* W1t   = (unsigned short*)p; p += (size_t)FIN * HH * CC1 * 2;  // 0.26 MB
    unsigned short* W2t   = (unsigned short*)p; p += (size_t)HH * CC1 * HH * CC2 * 2;
    float* asrc           = (float*)p;          p += (size_t)NN * HH * 4;
    float* adst           = (float*)p;          p += (size_t)NN * HH * 4;
    int* deg              = (int*)p;            p += (size_t)NN * 4;
    int* csr_off          = (int*)p;            p += (size_t)(NN + 1) * 4 + 12;   // keep alignment
    int* csr_pos          = (int*)p;            p += (size_t)NN * 4;
    int* csr_src          = (int*)p;            p += (size_t)ET * 4;

    hipMemsetAsync(deg, 0, NN * sizeof(int), stream);

    // casts / weight transposes
    cast_bf16<<<(NN * FIN / 4 + 255) / 256, 256, 0, stream>>>(x, xb, NN * FIN / 4);
    transpose_cast<<<(FIN * HH * CC1 + 255) / 256, 256, 0, stream>>>(W1, W1t, FIN, HH * CC1);
    transpose_cast<<<(HH * CC1 * HH * CC2 + 255) / 256, 256, 0, stream>>>(W2, W2t, HH * CC1, HH * CC2);

    // CSR build
    edge_histogram<<<(ET + 255) / 256, 256, 0, stream>>>(ei, deg);
    scan_offsets<<<1, 1024, 0, stream>>>(deg, csr_off, csr_pos);
    edge_scatter<<<(ET + 255) / 256, 256, 0, stream>>>(ei, csr_pos, csr_src);

    // layer 1 GEMM: h1 = x @ W1   [50000,256]@[256,512] -> bf16
    gemm_bf16<<<dim3((NN + 127) / 128, (HH * CC1) / 128), 256, 0, stream>>>(
        xb, W1t, h1b, NN, HH * CC1, FIN);

    attn_scores_bf16<<<dim3(NN, HH), 64, 0, stream>>>(h1b, a_src1, a_dst1, asrc, adst, CC1);
    aggregate_bf16<CC1, true><<<dim3(NN, HH), 64, 0, stream>>>(
        h1b, csr_off, csr_src, asrc, adst, b1, out1b);

    // layer 2 GEMM: h2 = out1 @ W2   [50000,512]@[512,256] -> bf16
    gemm_bf16<<<dim3((NN + 127) / 128, (HH * CC2) / 128), 256, 0, stream>>>(
        out1b, W2t, h2b, NN, HH * CC2, HH * CC1);

    attn_scores_bf16<<<dim3(NN, HH), 64, 0, stream>>>(h2b, a_src2, a_dst2, asrc, adst, CC2);
    aggregate_bf16<CC2, false><<<dim3(NN, HH), 64, 0, stream>>>(
        h2b, csr_off, csr_src, asrc, adst, b2, out2);

    // final: out = out2 @ Wf + bf   [50000,256]@[256,50] fp32
    gemm_f32<<<dim3((NN + 63) / 64, (NCLS + 63) / 64), 256, 0, stream>>>(
        out2, Wf, bf, out, NN, NCLS, HH * CC2);
}

// Round 4
// 579.184 us; speedup vs baseline: 2.2273x; 1.2565x over previous
//
#include <hip/hip_runtime.h>
#include <hip/hip_bf16.h>
#include <cmath>

// Problem constants
#define NN 50000
#define EE 800000
#define ET 850000   // EE + NN self loops
#define HH 4
#define CC1 128
#define CC2 64
#define FIN 256
#define NCLS 50

typedef __attribute__((ext_vector_type(8))) short   short8;
typedef __attribute__((ext_vector_type(8))) unsigned short ushort8;
typedef __attribute__((ext_vector_type(4))) unsigned short ushortx4;
typedef __attribute__((ext_vector_type(4))) float   floatx4;

__device__ __forceinline__ unsigned short f2bf(float f) {
    union { float f; unsigned int u; } x; x.f = f;
    unsigned int lsb = (x.u >> 16) & 1u;
    x.u += 0x7fffu + lsb;          // round-to-nearest-even
    return (unsigned short)(x.u >> 16);
}
__device__ __forceinline__ float bf2f(unsigned short b) {
    union { unsigned int u; float f; } x; x.u = ((unsigned int)b) << 16;
    return x.f;
}

// ---------------- cast fp32 -> bf16 (4 elems/thread) ------------------------
__global__ __launch_bounds__(256) void cast_bf16(
    const float* __restrict__ in, unsigned short* __restrict__ out, int n4)
{
    int t = blockIdx.x * blockDim.x + threadIdx.x;
    if (t >= n4) return;
    float4 v = *(const float4*)(in + 4 * (size_t)t);
    unsigned short r0 = f2bf(v.x), r1 = f2bf(v.y), r2 = f2bf(v.z), r3 = f2bf(v.w);
    unsigned int lo = (unsigned int)r0 | ((unsigned int)r1 << 16);
    unsigned int hi = (unsigned int)r2 | ((unsigned int)r3 << 16);
    *(uint2*)(out + 4 * (size_t)t) = make_uint2(lo, hi);
}

// ---------------- transpose + cast: W[K,N] f32 -> Wt[N,K] bf16 --------------
__global__ __launch_bounds__(256) void transpose_cast(
    const float* __restrict__ W, unsigned short* __restrict__ Wt, int K, int N)
{
    int t = blockIdx.x * blockDim.x + threadIdx.x;
    if (t >= K * N) return;
    int n = t / K, k = t - n * K;
    Wt[t] = f2bf(W[(size_t)k * N + n]);
}

// ---------------- bf16 MFMA GEMM: C[M,N] = A[M,K] @ Bt[N,K]^T ---------------
// 128x128 tile, 4 waves, 64x64/wave as 4x4 mfma 16x16x32 tiles. Output bf16.
__global__ __launch_bounds__(256) void gemm_bf16(
    const unsigned short* __restrict__ A,   // [M,K] bf16
    const unsigned short* __restrict__ Bt,  // [N,K] bf16
    unsigned short* __restrict__ C,         // [M,N] bf16
    int M, int N, int K)
{
    __shared__ unsigned short As[128 * 40];
    __shared__ unsigned short Bs[128 * 40];
    int tid  = threadIdx.x;
    int wave = tid >> 6;
    int lane = tid & 63;
    int wm = (wave >> 1) * 64;
    int wn = (wave & 1) * 64;
    int row0 = blockIdx.x * 128;
    int col0 = blockIdx.y * 128;

    int lm = lane & 15;
    int lq = lane >> 4;
    int kq = lq * 8;

    floatx4 acc[4][4] = {};

    int sr = tid >> 1;
    int sk = (tid & 1) * 16;

    for (int k0 = 0; k0 < K; k0 += 32) {
        ushort8 a0 = {0,0,0,0,0,0,0,0}, a1 = {0,0,0,0,0,0,0,0};
        int gr = row0 + sr;
        if (gr < M) {
            const unsigned short* ap = A + (size_t)gr * K + k0 + sk;
            a0 = *(const ushort8*)ap;
            a1 = *(const ushort8*)(ap + 8);
        }
        const unsigned short* bp = Bt + (size_t)(col0 + sr) * K + k0 + sk;
        ushort8 b0 = *(const ushort8*)bp;
        ushort8 b1 = *(const ushort8*)(bp + 8);

        __syncthreads();
        *(ushort8*)&As[sr * 40 + sk]     = a0;
        *(ushort8*)&As[sr * 40 + sk + 8] = a1;
        *(ushort8*)&Bs[sr * 40 + sk]     = b0;
        *(ushort8*)&Bs[sr * 40 + sk + 8] = b1;
        __syncthreads();

        short8 af[4], bf_[4];
        #pragma unroll
        for (int mt = 0; mt < 4; ++mt)
            af[mt] = *(const short8*)&As[(wm + mt * 16 + lm) * 40 + kq];
        #pragma unroll
        for (int nt = 0; nt < 4; ++nt)
            bf_[nt] = *(const short8*)&Bs[(wn + nt * 16 + lm) * 40 + kq];
        #pragma unroll
        for (int mt = 0; mt < 4; ++mt)
            #pragma unroll
            for (int nt = 0; nt < 4; ++nt)
                acc[mt][nt] = __builtin_amdgcn_mfma_f32_16x16x32_bf16(
                    af[mt], bf_[nt], acc[mt][nt], 0, 0, 0);
    }

    #pragma unroll
    for (int mt = 0; mt < 4; ++mt) {
        int rbase = row0 + wm + mt * 16 + lq * 4;
        #pragma unroll
        for (int nt = 0; nt < 4; ++nt) {
            int c = col0 + wn + nt * 16 + lm;
            #pragma unroll
            for (int r = 0; r < 4; ++r) {
                int gr = rbase + r;
                if (gr < M) C[(size_t)gr * N + c] = f2bf(acc[mt][nt][r]);
            }
        }
    }
}

// ------------- per-node attention halves, vectorized ------------------------
// one wave per node; lane covers CPL=HC/64 channels; 16 lanes per head.
template<int C>
__global__ __launch_bounds__(256) void attn_scores2(
    const unsigned short* __restrict__ h, const float* __restrict__ a_src,
    const float* __restrict__ a_dst, float* __restrict__ asrc,
    float* __restrict__ adst)
{
    constexpr int HC = HH * C;
    constexpr int CPL = HC / 64;   // 8 (C=128) or 4 (C=64)
    int wave = threadIdx.x >> 6;
    int lane = threadIdx.x & 63;
    int n = blockIdx.x * 4 + wave;
    if (n >= NN) return;
    int c0 = lane * CPL;
    int head = c0 / C;
    const unsigned short* hp = h + (size_t)n * HC + c0;
    float hv[CPL];
    if (CPL == 8) {
        ushort8 u = *(const ushort8*)hp;
        #pragma unroll
        for (int c = 0; c < 8; ++c) hv[c] = bf2f(u[c]);
    } else {
        ushortx4 u = *(const ushortx4*)hp;
        #pragma unroll
        for (int c = 0; c < 4; ++c) hv[c] = bf2f(u[c]);
    }
    float s1 = 0.f, s2 = 0.f;
    #pragma unroll
    for (int c = 0; c < CPL; ++c) {
        s1 += hv[c] * a_src[c0 + c];
        s2 += hv[c] * a_dst[c0 + c];
    }
    #pragma unroll
    for (int o = 8; o > 0; o >>= 1) {
        s1 += __shfl_xor(s1, o, 64);
        s2 += __shfl_xor(s2, o, 64);
    }
    if ((lane & 15) == 0) {
        asrc[n * HH + head] = s1;
        adst[n * HH + head] = s2;
    }
}

// ---------------- CSR build: histogram, scan, scatter -----------------------
__global__ void edge_histogram(const int* __restrict__ ei, int* __restrict__ deg)
{
    int t = blockIdx.x * blockDim.x + threadIdx.x;
    if (t >= ET) return;
    int dst = (t < EE) ? ei[EE + t] : (t - EE);
    atomicAdd(&deg[dst], 1);
}

__global__ __launch_bounds__(1024) void scan_offsets(
    const int* __restrict__ deg, int* __restrict__ off, int* __restrict__ pos)
{
    __shared__ int wsum[16];
    __shared__ int carry_s;
    int tid = threadIdx.x;
    int lane = tid & 63, wid = tid >> 6;
    if (tid == 0) carry_s = 0;
    __syncthreads();
    for (int base = 0; base < NN; base += 1024) {
        int i = base + tid;
        int v = (i < NN) ? deg[i] : 0;
        int s = v;
        #pragma unroll
        for (int o = 1; o < 64; o <<= 1) {
            int t = __shfl_up(s, o, 64);
            if (lane >= o) s += t;
        }
        if (lane == 63) wsum[wid] = s;
        __syncthreads();
        if (wid == 0 && lane < 16) {
            int w = wsum[lane];
            #pragma unroll
            for (int o = 1; o < 16; o <<= 1) {
                int t = __shfl_up(w, o, 64);
                if (lane >= o) w += t;
            }
            wsum[lane] = w;
        }
        __syncthreads();
        int woff = (wid == 0) ? 0 : wsum[wid - 1];
        int carry = carry_s;
        int excl = carry + woff + s - v;
        if (i < NN) { off[i] = excl; pos[i] = excl; }
        __syncthreads();
        if (tid == 1023) carry_s = carry + wsum[15];
        __syncthreads();
    }
    if (tid == 0) off[NN] = carry_s;
}

__global__ void edge_scatter(const int* __restrict__ ei,
                             int* __restrict__ pos, int* __restrict__ csr_src)
{
    int t = blockIdx.x * blockDim.x + threadIdx.x;
    if (t >= ET) return;
    int src, dst;
    if (t < EE) { src = ei[t]; dst = ei[EE + t]; }
    else        { src = t - EE; dst = t - EE; }
    int p = atomicAdd(&pos[dst], 1);
    csr_src[p] = src;
}

// ---- fused edge-softmax + aggregation + bias + ELU, chunk-64 structure -----
// one wave per (node, head-group). Wave covers 256 channels = NHW heads.
// Score phase: lane i computes exp-score of edge i (for NHW heads) -> LDS.
// Agg phase: src[j] via readlane (scalar), ex[j] via ds_read broadcast.
template<int C, bool OUT_BF16>
__global__ __launch_bounds__(64) void aggregate3(
    const unsigned short* __restrict__ h, const int* __restrict__ off,
    const int* __restrict__ csr_src, const float* __restrict__ asrc,
    const float* __restrict__ adst, const float* __restrict__ bias,
    void* __restrict__ out_v)
{
    constexpr int HC = HH * C;
    constexpr int NHW = 256 / C;       // heads per wave: 2 (C=128) or 4 (C=64)
    __shared__ float exlds[64 * NHW];
    int n = blockIdx.x;
    int g = blockIdx.y;
    int lane = threadIdx.x;
    int h0 = g * NHW;
    int coff = g * 256 + lane * 4;     // channel offset within the HC row
    int hl = (lane * 4) / C;           // local head of this lane

    int start = off[n], end = off[n + 1];
    float adv[NHW];
    #pragma unroll
    for (int k = 0; k < NHW; ++k) adv[k] = adst[n * HH + h0 + k];

    float dh[NHW];
    #pragma unroll
    for (int k = 0; k < NHW; ++k) dh[k] = 0.f;
    float acc0 = 0.f, acc1 = 0.f, acc2 = 0.f, acc3 = 0.f;

    for (int cb = start; cb < end; cb += 64) {
        int eidx = cb + lane;
        bool valid = eidx < end;
        int s_lane = csr_src[valid ? eidx : end - 1];

        // ---- score phase: this lane's edge, NHW heads ----
        if (NHW == 2) {
            float2 t = *(const float2*)(asrc + (size_t)s_lane * HH + h0);
            float e0 = t.x + adv[0]; e0 = (e0 > 0.f) ? e0 : 0.2f * e0;
            float e1 = t.y + adv[1]; e1 = (e1 > 0.f) ? e1 : 0.2f * e1;
            float x0 = valid ? __expf(e0) : 0.f;
            float x1 = valid ? __expf(e1) : 0.f;
            dh[0] += x0; dh[1] += x1;
            *(float2*)&exlds[lane * 2] = make_float2(x0, x1);
        } else {
            float4 t = *(const float4*)(asrc + (size_t)s_lane * HH);
            float e0 = t.x + adv[0]; e0 = (e0 > 0.f) ? e0 : 0.2f * e0;
            float e1 = t.y + adv[1]; e1 = (e1 > 0.f) ? e1 : 0.2f * e1;
            float e2 = t.z + adv[2]; e2 = (e2 > 0.f) ? e2 : 0.2f * e2;
            float e3 = t.w + adv[3]; e3 = (e3 > 0.f) ? e3 : 0.2f * e3;
            float x0 = valid ? __expf(e0) : 0.f;
            float x1 = valid ? __expf(e1) : 0.f;
            float x2 = valid ? __expf(e2) : 0.f;
            float x3 = valid ? __expf(e3) : 0.f;
            dh[0] += x0; dh[1] += x1; dh[2] += x2; dh[3] += x3;
            *(float4*)&exlds[lane * 4] = make_float4(x0, x1, x2, x3);
        }

        // ---- aggregation phase over this chunk ----
        int cnt = end - cb; if (cnt > 64) cnt = 64;
        int jj = 0;
        for (; jj + 4 <= cnt; jj += 4) {
            int s0 = __builtin_amdgcn_readlane(s_lane, jj + 0);
            int s1 = __builtin_amdgcn_readlane(s_lane, jj + 1);
            int s2 = __builtin_amdgcn_readlane(s_lane, jj + 2);
            int s3 = __builtin_amdgcn_readlane(s_lane, jj + 3);
            float x0 = exlds[(jj + 0) * NHW + hl];
            float x1 = exlds[(jj + 1) * NHW + hl];
            float x2 = exlds[(jj + 2) * NHW + hl];
            float x3 = exlds[(jj + 3) * NHW + hl];
            ushortx4 u0 = *(const ushortx4*)(h + (size_t)s0 * HC + coff);
            ushortx4 u1 = *(const ushortx4*)(h + (size_t)s1 * HC + coff);
            ushortx4 u2 = *(const ushortx4*)(h + (size_t)s2 * HC + coff);
            ushortx4 u3 = *(const ushortx4*)(h + (size_t)s3 * HC + coff);
            acc0 += x0 * bf2f(u0[0]) + x1 * bf2f(u1[0]) + x2 * bf2f(u2[0]) + x3 * bf2f(u3[0]);
            acc1 += x0 * bf2f(u0[1]) + x1 * bf2f(u1[1]) + x2 * bf2f(u2[1]) + x3 * bf2f(u3[1]);
            acc2 += x0 * bf2f(u0[2]) + x1 * bf2f(u1[2]) + x2 * bf2f(u2[2]) + x3 * bf2f(u3[2]);
            acc3 += x0 * bf2f(u0[3]) + x1 * bf2f(u1[3]) + x2 * bf2f(u2[3]) + x3 * bf2f(u3[3]);
        }
        for (; jj < cnt; ++jj) {
            int s0 = __builtin_amdgcn_readlane(s_lane, jj);
            float x0 = exlds[jj * NHW + hl];
            ushortx4 u0 = *(const ushortx4*)(h + (size_t)s0 * HC + coff);
            acc0 += x0 * bf2f(u0[0]);
            acc1 += x0 * bf2f(u0[1]);
            acc2 += x0 * bf2f(u0[2]);
            acc3 += x0 * bf2f(u0[3]);
        }
    }

    // wave-reduce per-head denominators (butterfly -> all lanes)
    #pragma unroll
    for (int k = 0; k < NHW; ++k)
        #pragma unroll
        for (int o = 32; o > 0; o >>= 1)
            dh[k] += __shfl_xor(dh[k], o, 64);

    float d;
    if (NHW == 2) d = (hl == 0) ? dh[0] : dh[1];
    else d = (hl == 0) ? dh[0] : ((hl == 1) ? dh[1] : ((hl == 2) ? dh[2] : dh[3]));
    float inv = 1.f / (d + 1e-16f);

    float4 bv = *(const float4*)(bias + coff);
    float u0 = acc0 * inv + bv.x; u0 = (u0 > 0.f) ? u0 : expm1f(u0);
    float u1 = acc1 * inv + bv.y; u1 = (u1 > 0.f) ? u1 : expm1f(u1);
    float u2 = acc2 * inv + bv.z; u2 = (u2 > 0.f) ? u2 : expm1f(u2);
    float u3 = acc3 * inv + bv.w; u3 = (u3 > 0.f) ? u3 : expm1f(u3);

    if (OUT_BF16) {
        unsigned int lo = (unsigned int)f2bf(u0) | ((unsigned int)f2bf(u1) << 16);
        unsigned int hi = (unsigned int)f2bf(u2) | ((unsigned int)f2bf(u3) << 16);
        *(uint2*)((unsigned short*)out_v + (size_t)n * HC + coff) = make_uint2(lo, hi);
    } else {
        *(float4*)((float*)out_v + (size_t)n * HC + coff) = make_float4(u0, u1, u2, u3);
    }
}

// ---------------- fp32 tiled GEMM (64x64) — final classifier layer ----------
__global__ __launch_bounds__(256) void gemm_f32(
    const float* __restrict__ A, const float* __restrict__ B,
    const float* __restrict__ bias, float* __restrict__ C,
    int M, int N, int K)
{
    __shared__ float As[16][64 + 4];
    __shared__ float Bs[16][64 + 4];
    int tid = threadIdx.x;
    int row0 = blockIdx.x * 64;
    int col0 = blockIdx.y * 64;
    int tx = tid & 15;
    int ty = tid >> 4;
    float acc[4][4] = {{0.f}};

    int a_r = tid >> 2;
    int a_c = (tid & 3) << 2;
    int b_r = tid >> 4;
    int b_c = (tid & 15) << 2;
    bool n4 = ((N & 3) == 0);

    for (int k0 = 0; k0 < K; k0 += 16) {
        {
            int gr = row0 + a_r;
            float4 v = make_float4(0.f, 0.f, 0.f, 0.f);
            if (gr < M) v = *(const float4*)(A + (size_t)gr * K + k0 + a_c);
            As[a_c + 0][a_r] = v.x;
            As[a_c + 1][a_r] = v.y;
            As[a_c + 2][a_r] = v.z;
            As[a_c + 3][a_r] = v.w;
        }
        {
            int gc = col0 + b_c;
            const float* bp = B + (size_t)(k0 + b_r) * N + gc;
            float4 v;
            if (n4 && gc + 3 < N) {
                v = *(const float4*)bp;
            } else {
                v.x = (gc + 0 < N) ? bp[0] : 0.f;
                v.y = (gc + 1 < N) ? bp[1] : 0.f;
                v.z = (gc + 2 < N) ? bp[2] : 0.f;
                v.w = (gc + 3 < N) ? bp[3] : 0.f;
            }
            Bs[b_r][b_c + 0] = v.x;
            Bs[b_r][b_c + 1] = v.y;
            Bs[b_r][b_c + 2] = v.z;
            Bs[b_r][b_c + 3] = v.w;
        }
        __syncthreads();
        #pragma unroll
        for (int k = 0; k < 16; ++k) {
            float a0 = As[k][ty * 4 + 0];
            float a1 = As[k][ty * 4 + 1];
            float a2 = As[k][ty * 4 + 2];
            float a3 = As[k][ty * 4 + 3];
            float b0 = Bs[k][tx * 4 + 0];
            float b1 = Bs[k][tx * 4 + 1];
            float b2 = Bs[k][tx * 4 + 2];
            float b3 = Bs[k][tx * 4 + 3];
            acc[0][0] += a0 * b0; acc[0][1] += a0 * b1; acc[0][2] += a0 * b2; acc[0][3] += a0 * b3;
            acc[1][0] += a1 * b0; acc[1][1] += a1 * b1; acc[1][2] += a1 * b2; acc[1][3] += a1 * b3;
            acc[2][0] += a2 * b0; acc[2][1] += a2 * b1; acc[2][2] += a2 * b2; acc[2][3] += a2 * b3;
            acc[3][0] += a3 * b0; acc[3][1] += a3 * b1; acc[3][2] += a3 * b2; acc[3][3] += a3 * b3;
        }
        __syncthreads();
    }
    #pragma unroll
    for (int i = 0; i < 4; ++i) {
        int r = row0 + ty * 4 + i;
        if (r >= M) continue;
        #pragma unroll
        for (int j = 0; j < 4; ++j) {
            int c = col0 + tx * 4 + j;
            if (c >= N) continue;
            float v = acc[i][j];
            if (bias) v += bias[c];
            C[(size_t)r * N + c] = v;
        }
    }
}

extern "C" void kernel_launch(void* const* d_in, const int* in_sizes, int n_in,
                              void* d_out, int out_size, void* d_ws, size_t ws_size,
                              hipStream_t stream) {
    const float* x      = (const float*)d_in[0];
    const int*   ei     = (const int*)d_in[1];
    const float* W1     = (const float*)d_in[2];
    const float* a_src1 = (const float*)d_in[3];
    const float* a_dst1 = (const float*)d_in[4];
    const float* b1     = (const float*)d_in[5];
    const float* W2     = (const float*)d_in[6];
    const float* a_src2 = (const float*)d_in[7];
    const float* a_dst2 = (const float*)d_in[8];
    const float* b2     = (const float*)d_in[9];
    const float* Wf     = (const float*)d_in[10];
    const float* bf     = (const float*)d_in[11];
    float* out = (float*)d_out;

    // workspace layout (bytes, all 16B-aligned)
    char* p = (char*)d_ws;
    unsigned short* xb    = (unsigned short*)p; p += (size_t)NN * FIN * 2;
    unsigned short* h1b   = (unsigned short*)p; p += (size_t)NN * HH * CC1 * 2;
    unsigned short* out1b = (unsigned short*)p; p += (size_t)NN * HH * CC1 * 2;
    unsigned short* h2b   = (unsigned short*)p; p += (size_t)NN * HH * CC2 * 2;
    float* out2           = (float*)p;          p += (size_t)NN * HH * CC2 * 4;
    unsigned short* W1t   = (unsigned short*)p; p += (size_t)FIN * HH * CC1 * 2;
    unsigned short* W2t   = (unsigned short*)p; p += (size_t)HH * CC1 * HH * CC2 * 2;
    float* asrc           = (float*)p;          p += (size_t)NN * HH * 4;
    float* adst           = (float*)p;          p += (size_t)NN * HH * 4;
    int* deg              = (int*)p;            p += (size_t)NN * 4;
    int* csr_off          = (int*)p;            p += (size_t)(NN + 1) * 4 + 12;
    int* csr_pos          = (int*)p;            p += (size_t)NN * 4;
    int* csr_src          = (int*)p;            p += (size_t)ET * 4;

    hipMemsetAsync(deg, 0, NN * sizeof(int), stream);

    // casts / weight transposes
    cast_bf16<<<(NN * FIN / 4 + 255) / 256, 256, 0, stream>>>(x, xb, NN * FIN / 4);
    transpose_cast<<<(FIN * HH * CC1 + 255) / 256, 256, 0, stream>>>(W1, W1t, FIN, HH * CC1);
    transpose_cast<<<(HH * CC1 * HH * CC2 + 255) / 256, 256, 0, stream>>>(W2, W2t, HH * CC1, HH * CC2);

    // CSR build
    edge_histogram<<<(ET + 255) / 256, 256, 0, stream>>>(ei, deg);
    scan_offsets<<<1, 1024, 0, stream>>>(deg, csr_off, csr_pos);
    edge_scatter<<<(ET + 255) / 256, 256, 0, stream>>>(ei, csr_pos, csr_src);

    // layer 1 GEMM: h1 = x @ W1   [50000,256]@[256,512] -> bf16
    gemm_bf16<<<dim3((NN + 127) / 128, (HH * CC1) / 128), 256, 0, stream>>>(
        xb, W1t, h1b, NN, HH * CC1, FIN);

    attn_scores2<CC1><<<(NN + 3) / 4, 256, 0, stream>>>(h1b, a_src1, a_dst1, asrc, adst);
    aggregate3<CC1, true><<<dim3(NN, 2), 64, 0, stream>>>(
        h1b, csr_off, csr_src, asrc, adst, b1, out1b);

    // layer 2 GEMM: h2 = out1 @ W2   [50000,512]@[512,256] -> bf16
    gemm_bf16<<<dim3((NN + 127) / 128, (HH * CC2) / 128), 256, 0, stream>>>(
        out1b, W2t, h2b, NN, HH * CC2, HH * CC1);

    attn_scores2<CC2><<<(NN + 3) / 4, 256, 0, stream>>>(h2b, a_src2, a_dst2, asrc, adst);
    aggregate3<CC2, false><<<dim3(NN, 1), 64, 0, stream>>>(
        h2b, csr_off, csr_src, asrc, adst, b2, out2);

    // final: out = out2 @ Wf + bf   [50000,256]@[256,50] fp32
    gemm_f32<<<dim3((NN + 63) / 64, (NCLS + 63) / 64), 256, 0, stream>>>(
        out2, Wf, bf, out, NN, NCLS, HH * CC2);
}

// Round 5
// 550.289 us; speedup vs baseline: 2.3443x; 1.0525x over previous
//
#include <hip/hip_runtime.h>
#include <hip/hip_bf16.h>
#include <cmath>

// Problem constants
#define NN 50000
#define EE 800000
#define ET 850000   // EE + NN self loops
#define HH 4
#define CC1 128
#define CC2 64
#define FIN 256
#define NCLS 50

typedef __attribute__((ext_vector_type(8))) short   short8;
typedef __attribute__((ext_vector_type(8))) unsigned short ushort8;
typedef __attribute__((ext_vector_type(4))) unsigned short ushortx4;
typedef __attribute__((ext_vector_type(4))) float   floatx4;

__device__ __forceinline__ unsigned short f2bf(float f) {
    union { float f; unsigned int u; } x; x.f = f;
    unsigned int lsb = (x.u >> 16) & 1u;
    x.u += 0x7fffu + lsb;          // round-to-nearest-even
    return (unsigned short)(x.u >> 16);
}
__device__ __forceinline__ float bf2f(unsigned short b) {
    union { unsigned int u; float f; } x; x.u = ((unsigned int)b) << 16;
    return x.f;
}

// async global->LDS, 16B per lane, wave-uniform LDS base + lane*16
typedef const __attribute__((address_space(1))) unsigned int* glds_gp_t;
typedef __attribute__((address_space(3))) unsigned int* glds_lp_t;
__device__ __forceinline__ void glds16(const void* g, void* l) {
    __builtin_amdgcn_global_load_lds((glds_gp_t)g, (glds_lp_t)l, 16, 0, 0);
}

// ---------------- cast fp32 -> bf16 (4 elems/thread) ------------------------
__global__ __launch_bounds__(256) void cast_bf16(
    const float* __restrict__ in, unsigned short* __restrict__ out, int n4)
{
    int t = blockIdx.x * blockDim.x + threadIdx.x;
    if (t >= n4) return;
    float4 v = *(const float4*)(in + 4 * (size_t)t);
    unsigned short r0 = f2bf(v.x), r1 = f2bf(v.y), r2 = f2bf(v.z), r3 = f2bf(v.w);
    unsigned int lo = (unsigned int)r0 | ((unsigned int)r1 << 16);
    unsigned int hi = (unsigned int)r2 | ((unsigned int)r3 << 16);
    *(uint2*)(out + 4 * (size_t)t) = make_uint2(lo, hi);
}

// ---------------- transpose + cast: W[K,N] f32 -> Wt[N,K] bf16 --------------
__global__ __launch_bounds__(256) void transpose_cast(
    const float* __restrict__ W, unsigned short* __restrict__ Wt, int K, int N)
{
    int t = blockIdx.x * blockDim.x + threadIdx.x;
    if (t >= K * N) return;
    int n = t / K, k = t - n * K;
    Wt[t] = f2bf(W[(size_t)k * N + n]);
}

// transpose + cast + zero-pad rows: W[K,N] f32 -> Wt[Npad,K] bf16
__global__ __launch_bounds__(256) void transpose_cast_pad(
    const float* __restrict__ W, unsigned short* __restrict__ Wt,
    int K, int N, int Npad)
{
    int t = blockIdx.x * blockDim.x + threadIdx.x;
    if (t >= K * Npad) return;
    int n = t / K, k = t - n * K;
    Wt[t] = (n < N) ? f2bf(W[(size_t)k * N + n]) : (unsigned short)0;
}

// ------- bf16 MFMA GEMM with global_load_lds staging (m97 structure) --------
// C[M,N] = A[M,K] @ Bt[N,K]^T, output bf16. N % 128 == 0, K % 32 == 0.
// LDS tiles unpadded [128][32] bf16 (row = 64 B): matches lane*16B DMA order.
__global__ __launch_bounds__(256) void gemm_bf16_v2(
    const unsigned short* __restrict__ A,
    const unsigned short* __restrict__ Bt,
    unsigned short* __restrict__ C,
    int M, int N, int K)
{
    __shared__ unsigned short As[128 * 32];
    __shared__ unsigned short Bs[128 * 32];
    int tid = threadIdx.x, wave = tid >> 6, lane = tid & 63;
    int wm = (wave >> 1) * 64, wn = (wave & 1) * 64;
    int row0 = blockIdx.x * 128, col0 = blockIdx.y * 128;
    int lm = lane & 15, lq = lane >> 4, kq = lq * 8;
    floatx4 acc[4][4] = {};

    // staging map: wave covers rows [wave*32, wave*32+32) in two 16-row DMAs;
    // lane l -> row l>>2, k-quarter (l&3)*8  (= contiguous lane*16B in LDS)
    int srow = wave * 32 + (lane >> 2);
    int skk  = (lane & 3) * 8;
    int gra0 = row0 + srow;      if (gra0 >= M) gra0 = M - 1;
    int gra1 = row0 + srow + 16; if (gra1 >= M) gra1 = M - 1;
    const unsigned short* ga0 = A + (size_t)gra0 * K + skk;
    const unsigned short* ga1 = A + (size_t)gra1 * K + skk;
    const unsigned short* gb0 = Bt + (size_t)(col0 + srow) * K + skk;
    const unsigned short* gb1 = Bt + (size_t)(col0 + srow + 16) * K + skk;
    unsigned short* la0 = &As[(wave * 32) * 32];
    unsigned short* la1 = &As[(wave * 32 + 16) * 32];
    unsigned short* lb0 = &Bs[(wave * 32) * 32];
    unsigned short* lb1 = &Bs[(wave * 32 + 16) * 32];

    for (int k0 = 0; k0 < K; k0 += 32) {
        __syncthreads();                 // prior frag reads done
        glds16(ga0 + k0, la0);
        glds16(ga1 + k0, la1);
        glds16(gb0 + k0, lb0);
        glds16(gb1 + k0, lb1);
        __syncthreads();                 // drains vmcnt -> LDS ready

        short8 af[4], bfr[4];
        #pragma unroll
        for (int mt = 0; mt < 4; ++mt)
            af[mt] = *(const short8*)&As[(wm + mt * 16 + lm) * 32 + kq];
        #pragma unroll
        for (int nt = 0; nt < 4; ++nt)
            bfr[nt] = *(const short8*)&Bs[(wn + nt * 16 + lm) * 32 + kq];
        #pragma unroll
        for (int mt = 0; mt < 4; ++mt)
            #pragma unroll
            for (int nt = 0; nt < 4; ++nt)
                acc[mt][nt] = __builtin_amdgcn_mfma_f32_16x16x32_bf16(
                    af[mt], bfr[nt], acc[mt][nt], 0, 0, 0);
    }

    // C/D layout: col = lane&15, row = (lane>>4)*4 + reg
    #pragma unroll
    for (int mt = 0; mt < 4; ++mt) {
        int rbase = row0 + wm + mt * 16 + lq * 4;
        #pragma unroll
        for (int nt = 0; nt < 4; ++nt) {
            int c = col0 + wn + nt * 16 + lm;
            #pragma unroll
            for (int r = 0; r < 4; ++r) {
                int gr = rbase + r;
                if (gr < M) C[(size_t)gr * N + c] = f2bf(acc[mt][nt][r]);
            }
        }
    }
}

// ---- final classifier: out[M,50] f32 = A[M,256]bf16 @ Bt[64,256]^T + bias --
__global__ __launch_bounds__(128) void gemm_final(
    const unsigned short* __restrict__ A,
    const unsigned short* __restrict__ Bt,   // [64,256], rows >= 50 are zero
    const float* __restrict__ bias,
    float* __restrict__ out, int M)
{
    __shared__ unsigned short As[128 * 40];
    __shared__ unsigned short Bs[64 * 40];
    int tid = threadIdx.x, wave = tid >> 6, lane = tid & 63;
    int row0 = blockIdx.x * 128;
    int lm = lane & 15, lq = lane >> 4, kq = lq * 8;
    floatx4 acc[4][4] = {};

    for (int k0 = 0; k0 < 256; k0 += 32) {
        int gr = row0 + tid; if (gr >= M) gr = M - 1;
        const unsigned short* ap = A + (size_t)gr * 256 + k0;
        ushort8 a0 = *(const ushort8*)ap;
        ushort8 a1 = *(const ushort8*)(ap + 8);
        ushort8 a2 = *(const ushort8*)(ap + 16);
        ushort8 a3 = *(const ushort8*)(ap + 24);
        const unsigned short* bp = Bt + (size_t)(tid >> 1) * 256 + k0 + (tid & 1) * 16;
        ushort8 b0 = *(const ushort8*)bp;
        ushort8 b1 = *(const ushort8*)(bp + 8);
        __syncthreads();
        *(ushort8*)&As[tid * 40 + 0]  = a0;
        *(ushort8*)&As[tid * 40 + 8]  = a1;
        *(ushort8*)&As[tid * 40 + 16] = a2;
        *(ushort8*)&As[tid * 40 + 24] = a3;
        *(ushort8*)&Bs[(tid >> 1) * 40 + (tid & 1) * 16]     = b0;
        *(ushort8*)&Bs[(tid >> 1) * 40 + (tid & 1) * 16 + 8] = b1;
        __syncthreads();

        short8 af[4], bfr[4];
        #pragma unroll
        for (int mt = 0; mt < 4; ++mt)
            af[mt] = *(const short8*)&As[(wave * 64 + mt * 16 + lm) * 40 + kq];
        #pragma unroll
        for (int nt = 0; nt < 4; ++nt)
            bfr[nt] = *(const short8*)&Bs[(nt * 16 + lm) * 40 + kq];
        #pragma unroll
        for (int mt = 0; mt < 4; ++mt)
            #pragma unroll
            for (int nt = 0; nt < 4; ++nt)
                acc[mt][nt] = __builtin_amdgcn_mfma_f32_16x16x32_bf16(
                    af[mt], bfr[nt], acc[mt][nt], 0, 0, 0);
    }

    #pragma unroll
    for (int mt = 0; mt < 4; ++mt) {
        int rbase = row0 + wave * 64 + mt * 16 + lq * 4;
        #pragma unroll
        for (int nt = 0; nt < 4; ++nt) {
            int c = nt * 16 + lm;
            if (c >= NCLS) continue;
            float bv = bias[c];
            #pragma unroll
            for (int r = 0; r < 4; ++r) {
                int gr = rbase + r;
                if (gr < M) out[(size_t)gr * NCLS + c] = acc[mt][nt][r] + bv;
            }
        }
    }
}

// ------------- per-node attention halves, vectorized ------------------------
template<int C>
__global__ __launch_bounds__(256) void attn_scores2(
    const unsigned short* __restrict__ h, const float* __restrict__ a_src,
    const float* __restrict__ a_dst, float* __restrict__ asrc,
    float* __restrict__ adst)
{
    constexpr int HC = HH * C;
    constexpr int CPL = HC / 64;   // 8 (C=128) or 4 (C=64)
    int wave = threadIdx.x >> 6;
    int lane = threadIdx.x & 63;
    int n = blockIdx.x * 4 + wave;
    if (n >= NN) return;
    int c0 = lane * CPL;
    int head = c0 / C;
    const unsigned short* hp = h + (size_t)n * HC + c0;
    float hv[CPL];
    if (CPL == 8) {
        ushort8 u = *(const ushort8*)hp;
        #pragma unroll
        for (int c = 0; c < 8; ++c) hv[c] = bf2f(u[c]);
    } else {
        ushortx4 u = *(const ushortx4*)hp;
        #pragma unroll
        for (int c = 0; c < 4; ++c) hv[c] = bf2f(u[c]);
    }
    float s1 = 0.f, s2 = 0.f;
    #pragma unroll
    for (int c = 0; c < CPL; ++c) {
        s1 += hv[c] * a_src[c0 + c];
        s2 += hv[c] * a_dst[c0 + c];
    }
    #pragma unroll
    for (int o = 8; o > 0; o >>= 1) {
        s1 += __shfl_xor(s1, o, 64);
        s2 += __shfl_xor(s2, o, 64);
    }
    if ((lane & 15) == 0) {
        asrc[n * HH + head] = s1;
        adst[n * HH + head] = s2;
    }
}

// ---------------- CSR build: histogram, scan, scatter -----------------------
__global__ void edge_histogram(const int* __restrict__ ei, int* __restrict__ deg)
{
    int t = blockIdx.x * blockDim.x + threadIdx.x;
    if (t >= ET) return;
    int dst = (t < EE) ? ei[EE + t] : (t - EE);
    atomicAdd(&deg[dst], 1);
}

__global__ __launch_bounds__(1024) void scan_offsets(
    const int* __restrict__ deg, int* __restrict__ off, int* __restrict__ pos)
{
    __shared__ int wsum[16];
    __shared__ int carry_s;
    int tid = threadIdx.x;
    int lane = tid & 63, wid = tid >> 6;
    if (tid == 0) carry_s = 0;
    __syncthreads();
    for (int base = 0; base < NN; base += 1024) {
        int i = base + tid;
        int v = (i < NN) ? deg[i] : 0;
        int s = v;
        #pragma unroll
        for (int o = 1; o < 64; o <<= 1) {
            int t = __shfl_up(s, o, 64);
            if (lane >= o) s += t;
        }
        if (lane == 63) wsum[wid] = s;
        __syncthreads();
        if (wid == 0 && lane < 16) {
            int w = wsum[lane];
            #pragma unroll
            for (int o = 1; o < 16; o <<= 1) {
                int t = __shfl_up(w, o, 64);
                if (lane >= o) w += t;
            }
            wsum[lane] = w;
        }
        __syncthreads();
        int woff = (wid == 0) ? 0 : wsum[wid - 1];
        int carry = carry_s;
        int excl = carry + woff + s - v;
        if (i < NN) { off[i] = excl; pos[i] = excl; }
        __syncthreads();
        if (tid == 1023) carry_s = carry + wsum[15];
        __syncthreads();
    }
    if (tid == 0) off[NN] = carry_s;
}

__global__ void edge_scatter(const int* __restrict__ ei,
                             int* __restrict__ pos, int* __restrict__ csr_src)
{
    int t = blockIdx.x * blockDim.x + threadIdx.x;
    if (t >= ET) return;
    int src, dst;
    if (t < EE) { src = ei[t]; dst = ei[EE + t]; }
    else        { src = t - EE; dst = t - EE; }
    int p = atomicAdd(&pos[dst], 1);
    csr_src[p] = src;
}

// ---- fused edge-softmax + aggregation + bias + ELU (8 ch/lane, bf16 out) ---
// One 64-thread block per node. LPE = HC/8 lanes cover one edge's channels;
// EPW = 64/LPE edges in flight per step (1 for layer1, 2 for layer2).
// Score phase: lane i -> exp-score of chunk edge i (4 heads) -> LDS (0-padded).
// Agg phase: edge src via readlane (scalar), ex via ds_read broadcast.
template<int C>
__global__ __launch_bounds__(64) void aggregate4(
    const unsigned short* __restrict__ h, const int* __restrict__ off,
    const int* __restrict__ csr_src, const float* __restrict__ asrc,
    const float* __restrict__ adst, const float* __restrict__ bias,
    unsigned short* __restrict__ outb)
{
    constexpr int HC = HH * C;          // 512 or 256
    constexpr int LPE = HC / 8;         // 64 or 32
    constexpr int EPW = 64 / LPE;       // 1 or 2
    __shared__ float exlds[64 * HH];
    int n = blockIdx.x;
    int lane = threadIdx.x;
    int el  = (EPW == 1) ? 0 : (lane >> 5);
    int lel = (EPW == 1) ? lane : (lane & 31);
    int coff = lel * 8;
    int hl = coff / C;                  // local head of this lane's 8 channels

    int start = off[n], end = off[n + 1];
    float4 advv = *(const float4*)(adst + (size_t)n * HH);
    float dh0 = 0.f, dh1 = 0.f, dh2 = 0.f, dh3 = 0.f;
    float acc[8] = {0.f, 0.f, 0.f, 0.f, 0.f, 0.f, 0.f, 0.f};

    for (int cb = start; cb < end; cb += 64) {
        int eidx = cb + lane;
        bool valid = eidx < end;
        int s_lane = csr_src[valid ? eidx : end - 1];
        float4 t = *(const float4*)(asrc + (size_t)s_lane * HH);
        float e0 = t.x + advv.x; e0 = e0 > 0.f ? e0 : 0.2f * e0;
        float e1 = t.y + advv.y; e1 = e1 > 0.f ? e1 : 0.2f * e1;
        float e2 = t.z + advv.z; e2 = e2 > 0.f ? e2 : 0.2f * e2;
        float e3 = t.w + advv.w; e3 = e3 > 0.f ? e3 : 0.2f * e3;
        float x0 = valid ? __expf(e0) : 0.f;
        float x1 = valid ? __expf(e1) : 0.f;
        float x2 = valid ? __expf(e2) : 0.f;
        float x3 = valid ? __expf(e3) : 0.f;
        dh0 += x0; dh1 += x1; dh2 += x2; dh3 += x3;
        __syncthreads();   // prior chunk's exlds reads complete
        *(float4*)&exlds[lane * 4] = make_float4(x0, x1, x2, x3);
        __syncthreads();   // writes visible

        int cnt = end - cb; if (cnt > 64) cnt = 64;
        int jmax = (cnt + 4 * EPW - 1) & ~(4 * EPW - 1);   // pad: ex == 0 there
        for (int jj = 0; jj < jmax; jj += 4 * EPW) {
            int sidx[4]; float xs[4]; ushort8 uv[4];
            #pragma unroll
            for (int u = 0; u < 4; ++u) {
                int e_lo = jj + u * EPW;
                if (EPW == 1) {
                    sidx[u] = __builtin_amdgcn_readlane(s_lane, e_lo);
                } else {
                    int sa = __builtin_amdgcn_readlane(s_lane, e_lo);
                    int sb = __builtin_amdgcn_readlane(s_lane, e_lo + 1);
                    sidx[u] = el ? sb : sa;
                }
                xs[u] = exlds[(e_lo + el) * 4 + hl];
                uv[u] = *(const ushort8*)(h + (size_t)sidx[u] * HC + coff);
            }
            #pragma unroll
            for (int u = 0; u < 4; ++u)
                #pragma unroll
                for (int c = 0; c < 8; ++c)
                    acc[c] += xs[u] * bf2f(uv[u][c]);
        }
    }

    #pragma unroll
    for (int o = 32; o > 0; o >>= 1) {
        dh0 += __shfl_xor(dh0, o, 64);
        dh1 += __shfl_xor(dh1, o, 64);
        dh2 += __shfl_xor(dh2, o, 64);
        dh3 += __shfl_xor(dh3, o, 64);
    }
    if (EPW == 2) {
        #pragma unroll
        for (int c = 0; c < 8; ++c)
            acc[c] += __shfl_xor(acc[c], 32, 64);
    }
    float d = (hl == 0) ? dh0 : (hl == 1) ? dh1 : (hl == 2) ? dh2 : dh3;
    float inv = 1.f / (d + 1e-16f);
    if (el == 0) {
        float4 b0 = *(const float4*)(bias + coff);
        float4 b1 = *(const float4*)(bias + coff + 4);
        float bb[8] = {b0.x, b0.y, b0.z, b0.w, b1.x, b1.y, b1.z, b1.w};
        unsigned int pk[4];
        #pragma unroll
        for (int c2 = 0; c2 < 4; ++c2) {
            float ua = acc[2 * c2]     * inv + bb[2 * c2];
            float ub = acc[2 * c2 + 1] * inv + bb[2 * c2 + 1];
            ua = ua > 0.f ? ua : expm1f(ua);
            ub = ub > 0.f ? ub : expm1f(ub);
            pk[c2] = (unsigned int)f2bf(ua) | ((unsigned int)f2bf(ub) << 16);
        }
        *(uint4*)(outb + (size_t)n * HC + coff) = make_uint4(pk[0], pk[1], pk[2], pk[3]);
    }
}

extern "C" void kernel_launch(void* const* d_in, const int* in_sizes, int n_in,
                              void* d_out, int out_size, void* d_ws, size_t ws_size,
                              hipStream_t stream) {
    const float* x      = (const float*)d_in[0];
    const int*   ei     = (const int*)d_in[1];
    const float* W1     = (const float*)d_in[2];
    const float* a_src1 = (const float*)d_in[3];
    const float* a_dst1 = (const float*)d_in[4];
    const float* b1     = (const float*)d_in[5];
    const float* W2     = (const float*)d_in[6];
    const float* a_src2 = (const float*)d_in[7];
    const float* a_dst2 = (const float*)d_in[8];
    const float* b2     = (const float*)d_in[9];
    const float* Wf     = (const float*)d_in[10];
    const float* bf     = (const float*)d_in[11];
    float* out = (float*)d_out;

    // workspace layout (all segments 16B-aligned)
    char* p = (char*)d_ws;
    unsigned short* xb    = (unsigned short*)p; p += (size_t)NN * FIN * 2;
    unsigned short* h1b   = (unsigned short*)p; p += (size_t)NN * HH * CC1 * 2;
    unsigned short* out1b = (unsigned short*)p; p += (size_t)NN * HH * CC1 * 2;
    unsigned short* h2b   = (unsigned short*)p; p += (size_t)NN * HH * CC2 * 2;
    unsigned short* out2b = (unsigned short*)p; p += (size_t)NN * HH * CC2 * 2;
    unsigned short* W1t   = (unsigned short*)p; p += (size_t)FIN * HH * CC1 * 2;
    unsigned short* W2t   = (unsigned short*)p; p += (size_t)HH * CC1 * HH * CC2 * 2;
    unsigned short* Wft   = (unsigned short*)p; p += (size_t)64 * HH * CC2 * 2;
    float* asrc           = (float*)p;          p += (size_t)NN * HH * 4;
    float* adst           = (float*)p;          p += (size_t)NN * HH * 4;
    int* deg              = (int*)p;            p += (size_t)NN * 4;
    int* csr_off          = (int*)p;            p += (size_t)(NN + 1) * 4 + 12;
    int* csr_pos          = (int*)p;            p += (size_t)NN * 4;
    int* csr_src          = (int*)p;            p += (size_t)ET * 4;

    hipMemsetAsync(deg, 0, NN * sizeof(int), stream);

    // casts / weight transposes
    cast_bf16<<<(NN * FIN / 4 + 255) / 256, 256, 0, stream>>>(x, xb, NN * FIN / 4);
    transpose_cast<<<(FIN * HH * CC1 + 255) / 256, 256, 0, stream>>>(W1, W1t, FIN, HH * CC1);
    transpose_cast<<<(HH * CC1 * HH * CC2 + 255) / 256, 256, 0, stream>>>(W2, W2t, HH * CC1, HH * CC2);
    transpose_cast_pad<<<(HH * CC2 * 64 + 255) / 256, 256, 0, stream>>>(Wf, Wft, HH * CC2, NCLS, 64);

    // CSR build
    edge_histogram<<<(ET + 255) / 256, 256, 0, stream>>>(ei, deg);
    scan_offsets<<<1, 1024, 0, stream>>>(deg, csr_off, csr_pos);
    edge_scatter<<<(ET + 255) / 256, 256, 0, stream>>>(ei, csr_pos, csr_src);

    // layer 1: h1 = x @ W1  [50000,256]@[256,512] -> bf16
    gemm_bf16_v2<<<dim3((NN + 127) / 128, (HH * CC1) / 128), 256, 0, stream>>>(
        xb, W1t, h1b, NN, HH * CC1, FIN);
    attn_scores2<CC1><<<(NN + 3) / 4, 256, 0, stream>>>(h1b, a_src1, a_dst1, asrc, adst);
    aggregate4<CC1><<<NN, 64, 0, stream>>>(h1b, csr_off, csr_src, asrc, adst, b1, out1b);

    // layer 2: h2 = out1 @ W2  [50000,512]@[512,256] -> bf16
    gemm_bf16_v2<<<dim3((NN + 127) / 128, (HH * CC2) / 128), 256, 0, stream>>>(
        out1b, W2t, h2b, NN, HH * CC2, HH * CC1);
    attn_scores2<CC2><<<(NN + 3) / 4, 256, 0, stream>>>(h2b, a_src2, a_dst2, asrc, adst);
    aggregate4<CC2><<<NN, 64, 0, stream>>>(h2b, csr_off, csr_src, asrc, adst, b2, out2b);

    // final classifier: out = out2 @ Wf + bf  [50000,256]@[256,50] -> f32
    gemm_final<<<(NN + 127) / 128, 128, 0, stream>>>(out2b, Wft, bf, out, NN);
}

// Round 6
// 512.297 us; speedup vs baseline: 2.5181x; 1.0742x over previous
//
#include <hip/hip_runtime.h>
#include <hip/hip_bf16.h>
#include <cmath>

// Problem constants
#define NN 50000
#define EE 800000
#define ET 850000   // EE + NN self loops
#define HH 4
#define CC1 128
#define CC2 64
#define FIN 256
#define NCLS 50

typedef __attribute__((ext_vector_type(8))) short   short8;
typedef __attribute__((ext_vector_type(8))) unsigned short ushort8;
typedef __attribute__((ext_vector_type(4))) unsigned short ushortx4;
typedef __attribute__((ext_vector_type(4))) float   floatx4;

__device__ __forceinline__ unsigned short f2bf(float f) {
    union { float f; unsigned int u; } x; x.f = f;
    unsigned int lsb = (x.u >> 16) & 1u;
    x.u += 0x7fffu + lsb;          // round-to-nearest-even
    return (unsigned short)(x.u >> 16);
}
__device__ __forceinline__ float bf2f(unsigned short b) {
    union { unsigned int u; float f; } x; x.u = ((unsigned int)b) << 16;
    return x.f;
}

// async global->LDS, 16B per lane, wave-uniform LDS base + lane*16
typedef const __attribute__((address_space(1))) unsigned int* glds_gp_t;
typedef __attribute__((address_space(3))) unsigned int* glds_lp_t;
__device__ __forceinline__ void glds16(const void* g, void* l) {
    __builtin_amdgcn_global_load_lds((glds_gp_t)g, (glds_lp_t)l, 16, 0, 0);
}

// ---------------- cast fp32 -> bf16 (4 elems/thread) ------------------------
__global__ __launch_bounds__(256) void cast_bf16(
    const float* __restrict__ in, unsigned short* __restrict__ out, int n4)
{
    int t = blockIdx.x * blockDim.x + threadIdx.x;
    if (t >= n4) return;
    float4 v = *(const float4*)(in + 4 * (size_t)t);
    unsigned short r0 = f2bf(v.x), r1 = f2bf(v.y), r2 = f2bf(v.z), r3 = f2bf(v.w);
    unsigned int lo = (unsigned int)r0 | ((unsigned int)r1 << 16);
    unsigned int hi = (unsigned int)r2 | ((unsigned int)r3 << 16);
    *(uint2*)(out + 4 * (size_t)t) = make_uint2(lo, hi);
}

// ---------------- transpose + cast: W[K,N] f32 -> Wt[N,K] bf16 --------------
__global__ __launch_bounds__(256) void transpose_cast(
    const float* __restrict__ W, unsigned short* __restrict__ Wt, int K, int N)
{
    int t = blockIdx.x * blockDim.x + threadIdx.x;
    if (t >= K * N) return;
    int n = t / K, k = t - n * K;
    Wt[t] = f2bf(W[(size_t)k * N + n]);
}

// transpose + cast + zero-pad rows: W[K,N] f32 -> Wt[Npad,K] bf16
__global__ __launch_bounds__(256) void transpose_cast_pad(
    const float* __restrict__ W, unsigned short* __restrict__ Wt,
    int K, int N, int Npad)
{
    int t = blockIdx.x * blockDim.x + threadIdx.x;
    if (t >= K * Npad) return;
    int n = t / K, k = t - n * K;
    Wt[t] = (n < N) ? f2bf(W[(size_t)k * N + n]) : (unsigned short)0;
}

// ------- bf16 MFMA GEMM with global_load_lds staging (m97 structure) --------
__global__ __launch_bounds__(256) void gemm_bf16_v2(
    const unsigned short* __restrict__ A,
    const unsigned short* __restrict__ Bt,
    unsigned short* __restrict__ C,
    int M, int N, int K)
{
    __shared__ unsigned short As[128 * 32];
    __shared__ unsigned short Bs[128 * 32];
    int tid = threadIdx.x, wave = tid >> 6, lane = tid & 63;
    int wm = (wave >> 1) * 64, wn = (wave & 1) * 64;
    int row0 = blockIdx.x * 128, col0 = blockIdx.y * 128;
    int lm = lane & 15, lq = lane >> 4, kq = lq * 8;
    floatx4 acc[4][4] = {};

    int srow = wave * 32 + (lane >> 2);
    int skk  = (lane & 3) * 8;
    int gra0 = row0 + srow;      if (gra0 >= M) gra0 = M - 1;
    int gra1 = row0 + srow + 16; if (gra1 >= M) gra1 = M - 1;
    const unsigned short* ga0 = A + (size_t)gra0 * K + skk;
    const unsigned short* ga1 = A + (size_t)gra1 * K + skk;
    const unsigned short* gb0 = Bt + (size_t)(col0 + srow) * K + skk;
    const unsigned short* gb1 = Bt + (size_t)(col0 + srow + 16) * K + skk;
    unsigned short* la0 = &As[(wave * 32) * 32];
    unsigned short* la1 = &As[(wave * 32 + 16) * 32];
    unsigned short* lb0 = &Bs[(wave * 32) * 32];
    unsigned short* lb1 = &Bs[(wave * 32 + 16) * 32];

    for (int k0 = 0; k0 < K; k0 += 32) {
        __syncthreads();
        glds16(ga0 + k0, la0);
        glds16(ga1 + k0, la1);
        glds16(gb0 + k0, lb0);
        glds16(gb1 + k0, lb1);
        __syncthreads();

        short8 af[4], bfr[4];
        #pragma unroll
        for (int mt = 0; mt < 4; ++mt)
            af[mt] = *(const short8*)&As[(wm + mt * 16 + lm) * 32 + kq];
        #pragma unroll
        for (int nt = 0; nt < 4; ++nt)
            bfr[nt] = *(const short8*)&Bs[(wn + nt * 16 + lm) * 32 + kq];
        #pragma unroll
        for (int mt = 0; mt < 4; ++mt)
            #pragma unroll
            for (int nt = 0; nt < 4; ++nt)
                acc[mt][nt] = __builtin_amdgcn_mfma_f32_16x16x32_bf16(
                    af[mt], bfr[nt], acc[mt][nt], 0, 0, 0);
    }

    #pragma unroll
    for (int mt = 0; mt < 4; ++mt) {
        int rbase = row0 + wm + mt * 16 + lq * 4;
        #pragma unroll
        for (int nt = 0; nt < 4; ++nt) {
            int c = col0 + wn + nt * 16 + lm;
            #pragma unroll
            for (int r = 0; r < 4; ++r) {
                int gr = rbase + r;
                if (gr < M) C[(size_t)gr * N + c] = f2bf(acc[mt][nt][r]);
            }
        }
    }
}

// ---- final classifier: out[M,50] f32 = A[M,256]bf16 @ Bt[64,256]^T + bias --
__global__ __launch_bounds__(128) void gemm_final(
    const unsigned short* __restrict__ A,
    const unsigned short* __restrict__ Bt,   // [64,256], rows >= 50 are zero
    const float* __restrict__ bias,
    float* __restrict__ out, int M)
{
    __shared__ unsigned short As[128 * 40];
    __shared__ unsigned short Bs[64 * 40];
    int tid = threadIdx.x, wave = tid >> 6, lane = tid & 63;
    int row0 = blockIdx.x * 128;
    int lm = lane & 15, lq = lane >> 4, kq = lq * 8;
    floatx4 acc[4][4] = {};

    for (int k0 = 0; k0 < 256; k0 += 32) {
        int gr = row0 + tid; if (gr >= M) gr = M - 1;
        const unsigned short* ap = A + (size_t)gr * 256 + k0;
        ushort8 a0 = *(const ushort8*)ap;
        ushort8 a1 = *(const ushort8*)(ap + 8);
        ushort8 a2 = *(const ushort8*)(ap + 16);
        ushort8 a3 = *(const ushort8*)(ap + 24);
        const unsigned short* bp = Bt + (size_t)(tid >> 1) * 256 + k0 + (tid & 1) * 16;
        ushort8 b0 = *(const ushort8*)bp;
        ushort8 b1 = *(const ushort8*)(bp + 8);
        __syncthreads();
        *(ushort8*)&As[tid * 40 + 0]  = a0;
        *(ushort8*)&As[tid * 40 + 8]  = a1;
        *(ushort8*)&As[tid * 40 + 16] = a2;
        *(ushort8*)&As[tid * 40 + 24] = a3;
        *(ushort8*)&Bs[(tid >> 1) * 40 + (tid & 1) * 16]     = b0;
        *(ushort8*)&Bs[(tid >> 1) * 40 + (tid & 1) * 16 + 8] = b1;
        __syncthreads();

        short8 af[4], bfr[4];
        #pragma unroll
        for (int mt = 0; mt < 4; ++mt)
            af[mt] = *(const short8*)&As[(wave * 64 + mt * 16 + lm) * 40 + kq];
        #pragma unroll
        for (int nt = 0; nt < 4; ++nt)
            bfr[nt] = *(const short8*)&Bs[(nt * 16 + lm) * 40 + kq];
        #pragma unroll
        for (int mt = 0; mt < 4; ++mt)
            #pragma unroll
            for (int nt = 0; nt < 4; ++nt)
                acc[mt][nt] = __builtin_amdgcn_mfma_f32_16x16x32_bf16(
                    af[mt], bfr[nt], acc[mt][nt], 0, 0, 0);
    }

    #pragma unroll
    for (int mt = 0; mt < 4; ++mt) {
        int rbase = row0 + wave * 64 + mt * 16 + lq * 4;
        #pragma unroll
        for (int nt = 0; nt < 4; ++nt) {
            int c = nt * 16 + lm;
            if (c >= NCLS) continue;
            float bv = bias[c];
            #pragma unroll
            for (int r = 0; r < 4; ++r) {
                int gr = rbase + r;
                if (gr < M) out[(size_t)gr * NCLS + c] = acc[mt][nt][r] + bv;
            }
        }
    }
}

// ------------- per-node attention halves, vectorized ------------------------
template<int C>
__global__ __launch_bounds__(256) void attn_scores2(
    const unsigned short* __restrict__ h, const float* __restrict__ a_src,
    const float* __restrict__ a_dst, float* __restrict__ asrc,
    float* __restrict__ adst)
{
    constexpr int HC = HH * C;
    constexpr int CPL = HC / 64;   // 8 (C=128) or 4 (C=64)
    int wave = threadIdx.x >> 6;
    int lane = threadIdx.x & 63;
    int n = blockIdx.x * 4 + wave;
    if (n >= NN) return;
    int c0 = lane * CPL;
    int head = c0 / C;
    const unsigned short* hp = h + (size_t)n * HC + c0;
    float hv[CPL];
    if (CPL == 8) {
        ushort8 u = *(const ushort8*)hp;
        #pragma unroll
        for (int c = 0; c < 8; ++c) hv[c] = bf2f(u[c]);
    } else {
        ushortx4 u = *(const ushortx4*)hp;
        #pragma unroll
        for (int c = 0; c < 4; ++c) hv[c] = bf2f(u[c]);
    }
    float s1 = 0.f, s2 = 0.f;
    #pragma unroll
    for (int c = 0; c < CPL; ++c) {
        s1 += hv[c] * a_src[c0 + c];
        s2 += hv[c] * a_dst[c0 + c];
    }
    #pragma unroll
    for (int o = 8; o > 0; o >>= 1) {
        s1 += __shfl_xor(s1, o, 64);
        s2 += __shfl_xor(s2, o, 64);
    }
    if ((lane & 15) == 0) {
        asrc[n * HH + head] = s1;
        adst[n * HH + head] = s2;
    }
}

// ---------------- CSR build: histogram, hierarchical scan, scatter ----------
__global__ void edge_histogram(const int* __restrict__ ei, int* __restrict__ deg)
{
    int t = blockIdx.x * blockDim.x + threadIdx.x;
    if (t >= ET) return;
    int dst = (t < EE) ? ei[EE + t] : (t - EE);
    atomicAdd(&deg[dst], 1);
}

// phase 1: partials[b] = sum(deg[b*2048 .. b*2048+2047])
__global__ __launch_bounds__(256) void scan_reduce(
    const int* __restrict__ deg, int* __restrict__ partials)
{
    int i0 = blockIdx.x * 2048 + threadIdx.x * 8;
    int s = 0;
    #pragma unroll
    for (int k = 0; k < 8; ++k) { int i = i0 + k; s += (i < NN) ? deg[i] : 0; }
    #pragma unroll
    for (int o = 32; o > 0; o >>= 1) s += __shfl_xor(s, o, 64);
    __shared__ int ws[4];
    int lane = threadIdx.x & 63, wid = threadIdx.x >> 6;
    if (lane == 0) ws[wid] = s;
    __syncthreads();
    if (threadIdx.x == 0) partials[blockIdx.x] = ws[0] + ws[1] + ws[2] + ws[3];
}

// phase 2: exclusive scan of <=64 partials, one wave
__global__ __launch_bounds__(64) void scan_partials(int* __restrict__ partials, int nb)
{
    int lane = threadIdx.x;
    int v = (lane < nb) ? partials[lane] : 0;
    int s = v;
    #pragma unroll
    for (int o = 1; o < 64; o <<= 1) {
        int t = __shfl_up(s, o, 64);
        if (lane >= o) s += t;
    }
    if (lane < nb) partials[lane] = s - v;
}

// phase 3: per-chunk exclusive scan + chunk base -> off, pos
__global__ __launch_bounds__(256) void scan_apply(
    const int* __restrict__ deg, const int* __restrict__ partials,
    int* __restrict__ off, int* __restrict__ pos)
{
    int i0 = blockIdx.x * 2048 + threadIdx.x * 8;
    int v[8]; int s = 0;
    #pragma unroll
    for (int k = 0; k < 8; ++k) {
        int i = i0 + k;
        v[k] = (i < NN) ? deg[i] : 0;
        s += v[k];
    }
    int lane = threadIdx.x & 63, wid = threadIdx.x >> 6;
    int sc = s;
    #pragma unroll
    for (int o = 1; o < 64; o <<= 1) {
        int t = __shfl_up(sc, o, 64);
        if (lane >= o) sc += t;
    }
    __shared__ int ws[4];
    if (lane == 63) ws[wid] = sc;
    __syncthreads();
    int woff = partials[blockIdx.x];
    for (int w = 0; w < wid; ++w) woff += ws[w];
    int excl = woff + sc - s;
    #pragma unroll
    for (int k = 0; k < 8; ++k) {
        int i = i0 + k;
        if (i < NN) { off[i] = excl; pos[i] = excl; }
        excl += v[k];
    }
    if (blockIdx.x == 0 && threadIdx.x == 0) off[NN] = ET;  // total is a constant
}

__global__ void edge_scatter(const int* __restrict__ ei,
                             int* __restrict__ pos, int* __restrict__ csr_src)
{
    int t = blockIdx.x * blockDim.x + threadIdx.x;
    if (t >= ET) return;
    int src, dst;
    if (t < EE) { src = ei[t]; dst = ei[EE + t]; }
    else        { src = t - EE; dst = t - EE; }
    int p = atomicAdd(&pos[dst], 1);
    csr_src[p] = src;
}

// ---- fused edge-softmax + aggregation + bias + ELU (4 waves/block) ---------
// Wave w of a 256-thread block handles node blockIdx.x*4+w independently.
// No __syncthreads: per-wave LDS broadcast is wave-synchronous.
template<int C>
__global__ __launch_bounds__(256) void aggregate5(
    const unsigned short* __restrict__ h, const int* __restrict__ off,
    const int* __restrict__ csr_src, const float* __restrict__ asrc,
    const float* __restrict__ adst, const float* __restrict__ bias,
    unsigned short* __restrict__ outb)
{
    constexpr int HC = HH * C;          // 512 or 256
    constexpr int LPE = HC / 8;         // 64 or 32 lanes per edge-row
    constexpr int EPW = 64 / LPE;       // 1 or 2 edges in flight per wave
    __shared__ float exlds_all[4][64 * HH];
    int wave = threadIdx.x >> 6;
    int lane = threadIdx.x & 63;
    int n = blockIdx.x * 4 + wave;
    if (n >= NN) return;
    float* exlds = exlds_all[wave];
    int el  = (EPW == 1) ? 0 : (lane >> 5);
    int lel = (EPW == 1) ? lane : (lane & 31);
    int coff = lel * 8;
    int hl = coff / C;

    int start = off[n], end = off[n + 1];
    float4 advv = *(const float4*)(adst + (size_t)n * HH);
    float dh0 = 0.f, dh1 = 0.f, dh2 = 0.f, dh3 = 0.f;
    float acc[8] = {0.f, 0.f, 0.f, 0.f, 0.f, 0.f, 0.f, 0.f};

    for (int cb = start; cb < end; cb += 64) {
        int eidx = cb + lane;
        bool valid = eidx < end;
        int s_lane = csr_src[valid ? eidx : end - 1];
        float4 t = *(const float4*)(asrc + (size_t)s_lane * HH);
        float e0 = t.x + advv.x; e0 = e0 > 0.f ? e0 : 0.2f * e0;
        float e1 = t.y + advv.y; e1 = e1 > 0.f ? e1 : 0.2f * e1;
        float e2 = t.z + advv.z; e2 = e2 > 0.f ? e2 : 0.2f * e2;
        float e3 = t.w + advv.w; e3 = e3 > 0.f ? e3 : 0.2f * e3;
        float x0 = valid ? __expf(e0) : 0.f;
        float x1 = valid ? __expf(e1) : 0.f;
        float x2 = valid ? __expf(e2) : 0.f;
        float x3 = valid ? __expf(e3) : 0.f;
        dh0 += x0; dh1 += x1; dh2 += x2; dh3 += x3;
        *(float4*)&exlds[lane * 4] = make_float4(x0, x1, x2, x3);
        // wave-synchronous: compiler emits lgkmcnt wait before the reads below

        int cnt = end - cb; if (cnt > 64) cnt = 64;
        int jmax = (cnt + 4 * EPW - 1) & ~(4 * EPW - 1);   // pad: ex == 0 there
        for (int jj = 0; jj < jmax; jj += 4 * EPW) {
            int sidx[4]; float xs[4]; ushort8 uv[4];
            #pragma unroll
            for (int u = 0; u < 4; ++u) {
                int e_lo = jj + u * EPW;
                if (EPW == 1) {
                    sidx[u] = __builtin_amdgcn_readlane(s_lane, e_lo);
                } else {
                    int sa = __builtin_amdgcn_readlane(s_lane, e_lo);
                    int sb = __builtin_amdgcn_readlane(s_lane, e_lo + 1);
                    sidx[u] = el ? sb : sa;
                }
                xs[u] = exlds[(e_lo + el) * 4 + hl];
                uv[u] = *(const ushort8*)(h + (size_t)sidx[u] * HC + coff);
            }
            #pragma unroll
            for (int u = 0; u < 4; ++u)
                #pragma unroll
                for (int c = 0; c < 8; ++c)
                    acc[c] += xs[u] * bf2f(uv[u][c]);
        }
    }

    #pragma unroll
    for (int o = 32; o > 0; o >>= 1) {
        dh0 += __shfl_xor(dh0, o, 64);
        dh1 += __shfl_xor(dh1, o, 64);
        dh2 += __shfl_xor(dh2, o, 64);
        dh3 += __shfl_xor(dh3, o, 64);
    }
    if (EPW == 2) {
        #pragma unroll
        for (int c = 0; c < 8; ++c)
            acc[c] += __shfl_xor(acc[c], 32, 64);
    }
    float d = (hl == 0) ? dh0 : (hl == 1) ? dh1 : (hl == 2) ? dh2 : dh3;
    float inv = 1.f / (d + 1e-16f);
    if (el == 0) {
        float4 b0 = *(const float4*)(bias + coff);
        float4 b1 = *(const float4*)(bias + coff + 4);
        float bb[8] = {b0.x, b0.y, b0.z, b0.w, b1.x, b1.y, b1.z, b1.w};
        unsigned int pk[4];
        #pragma unroll
        for (int c2 = 0; c2 < 4; ++c2) {
            float ua = acc[2 * c2]     * inv + bb[2 * c2];
            float ub = acc[2 * c2 + 1] * inv + bb[2 * c2 + 1];
            ua = ua > 0.f ? ua : expm1f(ua);
            ub = ub > 0.f ? ub : expm1f(ub);
            pk[c2] = (unsigned int)f2bf(ua) | ((unsigned int)f2bf(ub) << 16);
        }
        *(uint4*)(outb + (size_t)n * HC + coff) = make_uint4(pk[0], pk[1], pk[2], pk[3]);
    }
}

extern "C" void kernel_launch(void* const* d_in, const int* in_sizes, int n_in,
                              void* d_out, int out_size, void* d_ws, size_t ws_size,
                              hipStream_t stream) {
    const float* x      = (const float*)d_in[0];
    const int*   ei     = (const int*)d_in[1];
    const float* W1     = (const float*)d_in[2];
    const float* a_src1 = (const float*)d_in[3];
    const float* a_dst1 = (const float*)d_in[4];
    const float* b1     = (const float*)d_in[5];
    const float* W2     = (const float*)d_in[6];
    const float* a_src2 = (const float*)d_in[7];
    const float* a_dst2 = (const float*)d_in[8];
    const float* b2     = (const float*)d_in[9];
    const float* Wf     = (const float*)d_in[10];
    const float* bf     = (const float*)d_in[11];
    float* out = (float*)d_out;

    // workspace layout (all segments 16B-aligned)
    char* p = (char*)d_ws;
    unsigned short* xb    = (unsigned short*)p; p += (size_t)NN * FIN * 2;
    unsigned short* h1b   = (unsigned short*)p; p += (size_t)NN * HH * CC1 * 2;
    unsigned short* out1b = (unsigned short*)p; p += (size_t)NN * HH * CC1 * 2;
    unsigned short* h2b   = (unsigned short*)p; p += (size_t)NN * HH * CC2 * 2;
    unsigned short* out2b = (unsigned short*)p; p += (size_t)NN * HH * CC2 * 2;
    unsigned short* W1t   = (unsigned short*)p; p += (size_t)FIN * HH * CC1 * 2;
    unsigned short* W2t   = (unsigned short*)p; p += (size_t)HH * CC1 * HH * CC2 * 2;
    unsigned short* Wft   = (unsigned short*)p; p += (size_t)64 * HH * CC2 * 2;
    float* asrc           = (float*)p;          p += (size_t)NN * HH * 4;
    float* adst           = (float*)p;          p += (size_t)NN * HH * 4;
    int* deg              = (int*)p;            p += (size_t)NN * 4;
    int* csr_off          = (int*)p;            p += (size_t)(NN + 1) * 4 + 12;
    int* csr_pos          = (int*)p;            p += (size_t)NN * 4;
    int* csr_src          = (int*)p;            p += (size_t)ET * 4;
    int* partials         = (int*)p;            p += 64 * 4;

    hipMemsetAsync(deg, 0, NN * sizeof(int), stream);

    // casts / weight transposes
    cast_bf16<<<(NN * FIN / 4 + 255) / 256, 256, 0, stream>>>(x, xb, NN * FIN / 4);
    transpose_cast<<<(FIN * HH * CC1 + 255) / 256, 256, 0, stream>>>(W1, W1t, FIN, HH * CC1);
    transpose_cast<<<(HH * CC1 * HH * CC2 + 255) / 256, 256, 0, stream>>>(W2, W2t, HH * CC1, HH * CC2);
    transpose_cast_pad<<<(HH * CC2 * 64 + 255) / 256, 256, 0, stream>>>(Wf, Wft, HH * CC2, NCLS, 64);

    // CSR build (hierarchical scan: 50000 -> 25 chunks of 2048)
    const int NB = (NN + 2047) / 2048;   // 25
    edge_histogram<<<(ET + 255) / 256, 256, 0, stream>>>(ei, deg);
    scan_reduce<<<NB, 256, 0, stream>>>(deg, partials);
    scan_partials<<<1, 64, 0, stream>>>(partials, NB);
    scan_apply<<<NB, 256, 0, stream>>>(deg, partials, csr_off, csr_pos);
    edge_scatter<<<(ET + 255) / 256, 256, 0, stream>>>(ei, csr_pos, csr_src);

    // layer 1: h1 = x @ W1  [50000,256]@[256,512] -> bf16
    gemm_bf16_v2<<<dim3((NN + 127) / 128, (HH * CC1) / 128), 256, 0, stream>>>(
        xb, W1t, h1b, NN, HH * CC1, FIN);
    attn_scores2<CC1><<<(NN + 3) / 4, 256, 0, stream>>>(h1b, a_src1, a_dst1, asrc, adst);
    aggregate5<CC1><<<(NN + 3) / 4, 256, 0, stream>>>(h1b, csr_off, csr_src, asrc, adst, b1, out1b);

    // layer 2: h2 = out1 @ W2  [50000,512]@[512,256] -> bf16
    gemm_bf16_v2<<<dim3((NN + 127) / 128, (HH * CC2) / 128), 256, 0, stream>>>(
        out1b, W2t, h2b, NN, HH * CC2, HH * CC1);
    attn_scores2<CC2><<<(NN + 3) / 4, 256, 0, stream>>>(h2b, a_src2, a_dst2, asrc, adst);
    aggregate5<CC2><<<(NN + 3) / 4, 256, 0, stream>>>(h2b, csr_off, csr_src, asrc, adst, b2, out2b);

    // final classifier: out = out2 @ Wf + bf  [50000,256]@[256,50] -> f32
    gemm_final<<<(NN + 127) / 128, 128, 0, stream>>>(out2b, Wft, bf, out, NN);
}